// Round 13
// baseline (1327.179 us; speedup 1.0000x reference)
//
#include <hip/hip_runtime.h>
#include <math.h>

// ULOSD keypoint autoencoder, fp32 direct convolutions.
// Round 16: R15 post-mortem -- float2 change was a codegen no-op (identical
// 6225920 conflicts; compiler had already widened R14's reads) and conflicts
// are only ~5% of tile_lds time anyway. tile_lds ~= s1r2 (202 vs 195): revert
// enc1/enc3 to R13 s1r2 (1192us best). Real floor recalc with MEASURED v_fma
// ceiling (m07: 103TF): enc-class layers floor ~94us; layers at ~2x.
// Winning lever (R8/R12/R13): FMA-per-loaded-float at >=1024 blocks.
// This round: enc3 -> conv64_lds: full 64x64 plane staged per block
// ([64][68], 34.8KB dbuf, 4 blocks/CU), 256 threads x 4x4 outputs, NC2.
// 0.5 global loads/output (3x denser than s1r2), 288 FMA/ci/thread between
// barriers, issue-early/write-late (conv32_lds proven pattern).
// Everything else exactly R13.

enum { ACT_ID = 0, ACT_LRELU = 1, ACT_SOFTPLUS = 2, ACT_RELU = 3 };

template<int ACT>
__device__ __forceinline__ float act_fn(float x) {
  if (ACT == ACT_LRELU)    return x >= 0.f ? x : 0.2f * x;
  if (ACT == ACT_SOFTPLUS) return fmaxf(x, 0.f) + log1pf(expf(-fabsf(x)));
  if (ACT == ACT_RELU)     return fmaxf(x, 0.f);
  return x;
}

// ---------------- 64x64 stride-1 conv, full-plane LDS, 4x4 out per thread ------
// 256 threads = 16x16 grid of 4x4 output blocks. Plane [64] rows x stride 68.
// SAME-pad handled by selects (edge threads only). Input row gr = 4*tr-1+d
// feeds output rows o in {d-1,d,d+1} with weight row wr = d-o+1.
template<int ACT, int NC, int CIN>
__global__ __launch_bounds__(256)
void conv64_lds(const float* __restrict__ in, const float* __restrict__ w,
                const float* __restrict__ bias, float* __restrict__ out,
                int Cout) {
  __shared__ float pl[2][64 * 68];
  const int cogs = Cout / NC;
  const int gx  = blockIdx.x;           // b*cogs + cog
  const int cog = gx % cogs;
  const int b   = gx / cogs;
  const int co0 = cog * NC;
  const int t   = threadIdx.x;
  const int tr  = t >> 4;               // 0..15
  const int tc  = t & 15;               // 0..15
  const int y0  = tr * 4, x0 = tc * 4;  // output 4x4 block origin

  const float* ib = in + (size_t)b * CIN * 4096;
  const int lbase = tr * 68 + 4 * tc;   // stage slot: row 16k+tr, col 4*tc

  { // stage plane 0: 4 coalesced float4 per thread
    #pragma unroll
    for (int k = 0; k < 4; ++k) {
      float4 g4 = *(const float4*)(ib + k * 1024 + 4 * t);
      *(float4*)&pl[0][lbase + k * 16 * 68] = g4;
    }
  }
  __syncthreads();

  float acc[NC][4][4];
  #pragma unroll
  for (int u = 0; u < NC; ++u)
    #pragma unroll
    for (int o = 0; o < 4; ++o)
      #pragma unroll
      for (int q = 0; q < 4; ++q) acc[u][o][q] = 0.f;

  int cur = 0;
  #pragma unroll 1
  for (int ci = 0; ci < CIN; ++ci) {
    const bool more = (ci + 1 < CIN);
    float4 g[4];
    if (more) {
      const float* p = ib + (size_t)(ci + 1) * 4096;
      #pragma unroll
      for (int k = 0; k < 4; ++k) g[k] = *(const float4*)(p + k * 1024 + 4 * t);
    }

    const float* P = pl[cur];
    const float* wci = w + ((size_t)co0 * CIN + ci) * 9;
    #pragma unroll
    for (int dd = 0; dd < 6; ++dd) {       // input rows y0-1 .. y0+4
      const int d  = dd - 1;
      const int gr = y0 + d;
      const bool ok = (gr >= 0) && (gr < 64);
      const int grc = ok ? gr : 0;
      const float* row = P + grc * 68 + x0;
      const float  lf = (tc > 0)  ? row[-1] : 0.f;   // col x0-1 (SAME pad)
      const float4 m  = *(const float4*)row;         // cols x0..x0+3, 16B aligned
      const float  rf = (tc < 15) ? row[4]  : 0.f;   // col x0+4
      float v[6];
      v[0] = ok ? lf  : 0.f;
      v[1] = ok ? m.x : 0.f;
      v[2] = ok ? m.y : 0.f;
      v[3] = ok ? m.z : 0.f;
      v[4] = ok ? m.w : 0.f;
      v[5] = ok ? rf  : 0.f;
      #pragma unroll
      for (int o = 0; o < 4; ++o) {
        if (o < d - 1 || o > d + 1) continue;        // compile-time pruned
        const int wr = d - o + 1;                    // weight row 0..2
        #pragma unroll
        for (int u = 0; u < NC; ++u) {
          const float* wp = wci + (size_t)u * CIN * 9 + wr * 3;  // s_loads
          const float w0 = wp[0], w1 = wp[1], w2 = wp[2];
          #pragma unroll
          for (int q = 0; q < 4; ++q)
            acc[u][o][q] += v[q] * w0 + v[q + 1] * w1 + v[q + 2] * w2;
        }
      }
    }
    if (more) {
      float* dst = pl[cur ^ 1];
      #pragma unroll
      for (int k = 0; k < 4; ++k) *(float4*)&dst[lbase + k * 16 * 68] = g[k];
    }
    __syncthreads();
    cur ^= 1;
  }

  #pragma unroll
  for (int u = 0; u < NC; ++u) {
    const float bv = bias[co0 + u];
    float* op = out + ((size_t)(b * Cout + co0 + u) * 64 + y0) * 64 + x0;
    #pragma unroll
    for (int o = 0; o < 4; ++o) {
      float4 r4;
      r4.x = act_fn<ACT>(acc[u][o][0] + bv);
      r4.y = act_fn<ACT>(acc[u][o][1] + bv);
      r4.z = act_fn<ACT>(acc[u][o][2] + bv);
      r4.w = act_fn<ACT>(acc[u][o][3] + bv);
      *(float4*)(op + o * 64) = r4;
    }
  }
}

// ---------------- 32x32 stride-1 conv, LDS plane-staged, 2x2 out per thread ----
template<int ACT, int NC, int CIN>
__global__ __launch_bounds__(256)
void conv32_lds(const float* __restrict__ in, const float* __restrict__ w,
                const float* __restrict__ bias, float* __restrict__ out,
                int Cout) {
  __shared__ float pl[2][32 * 36];
  const int cogs = Cout / NC;
  const int gx  = blockIdx.x;           // b*cogs + cog
  const int cog = gx % cogs;
  const int b   = gx / cogs;
  const int co0 = cog * NC;
  const int t   = threadIdx.x;
  const int x0  = (t & 15) * 2;         // output cols x0, x0+1
  const int y0  = (t >> 4) * 2;         // output rows y0, y0+1

  const float* ib = in + (size_t)b * CIN * 1024;
  const int lx = (t >> 3) * 36 + (t & 7) * 4;   // this thread's LDS stage slot

  {
    float4 g0 = *(const float4*)(ib + t * 4);
    *(float4*)&pl[0][lx] = g0;
  }
  __syncthreads();

  const bool okT = (y0 > 0), okB = (y0 + 2 < 32);
  const bool okL = (x0 > 0), okR = (x0 + 2 < 32);

  float acc[NC][2][2];
  #pragma unroll
  for (int u = 0; u < NC; ++u)
    #pragma unroll
    for (int o = 0; o < 2; ++o) { acc[u][o][0] = 0.f; acc[u][o][1] = 0.f; }

  int cur = 0;
  #pragma unroll 1
  for (int ci = 0; ci < CIN; ++ci) {
    const bool more = (ci + 1 < CIN);
    float4 g = {0.f, 0.f, 0.f, 0.f};
    if (more) g = *(const float4*)(ib + (size_t)(ci + 1) * 1024 + t * 4);

    const float* P = pl[cur];
    const float* wci = w + ((size_t)co0 * CIN + ci) * 9;
    #pragma unroll
    for (int r = 0; r < 4; ++r) {
      const bool ok = (r == 0) ? okT : ((r == 3) ? okB : true);
      const int ry = ok ? (y0 - 1 + r) : 0;
      const int base = ry * 36 + x0;
      float v[4];
      v[0] = (ok && okL) ? P[base - 1] : 0.f;
      v[1] = ok ? P[base]     : 0.f;
      v[2] = ok ? P[base + 1] : 0.f;
      v[3] = (ok && okR) ? P[base + 2] : 0.f;
      #pragma unroll
      for (int u = 0; u < NC; ++u) {
        const float* wp = wci + (size_t)u * CIN * 9;
        if (r <= 2) {
          const float w0 = wp[r * 3], w1 = wp[r * 3 + 1], w2 = wp[r * 3 + 2];
          acc[u][0][0] += v[0] * w0 + v[1] * w1 + v[2] * w2;
          acc[u][0][1] += v[1] * w0 + v[2] * w1 + v[3] * w2;
        }
        if (r >= 1) {
          const float w0 = wp[(r-1) * 3], w1 = wp[(r-1) * 3 + 1], w2 = wp[(r-1) * 3 + 2];
          acc[u][1][0] += v[0] * w0 + v[1] * w1 + v[2] * w2;
          acc[u][1][1] += v[1] * w0 + v[2] * w1 + v[3] * w2;
        }
      }
    }
    if (more) *(float4*)&pl[cur ^ 1][lx] = g;
    __syncthreads();
    cur ^= 1;
  }

  #pragma unroll
  for (int u = 0; u < NC; ++u) {
    const float bv = bias[co0 + u];
    float* op = out + ((size_t)(b * Cout + co0 + u) * 32 + y0) * 32 + x0;
    float2 r0, r1;
    r0.x = act_fn<ACT>(acc[u][0][0] + bv); r0.y = act_fn<ACT>(acc[u][0][1] + bv);
    r1.x = act_fn<ACT>(acc[u][1][0] + bv); r1.y = act_fn<ACT>(acc[u][1][1] + bv);
    *(float2*)op = r0;
    *(float2*)(op + 32) = r1;
  }
}

// ---------------- stride-1 3x3 SAME conv, 2 output rows x CPT cols, NC couts ---
template<int ACT, int NC, int CPT, int CIN>
__global__ __launch_bounds__(256)
void conv_s1r2(const float* __restrict__ in, const float* __restrict__ w,
               const float* __restrict__ bias, float* __restrict__ out,
               int Cout, int H, int W) {
  const int cogs = Cout / NC;
  const int gx  = blockIdx.x;           // b*cogs + cog
  const int cog = gx % cogs;
  const int b   = gx / cogs;
  const int co0 = cog * NC;
  const int Wq  = W / CPT;
  const int Hp  = H >> 1;               // row pairs
  const int items = Hp * Wq;
  const int item  = blockIdx.y * 256 + threadIdx.x;
  if (item >= items) return;
  const int yp = item / Wq;
  const int x0 = (item - yp * Wq) * CPT;
  const int y0 = 2 * yp;                // output rows y0, y0+1; input y0-1..y0+2

  const int HW = H * W;
  const float* ib = in + (size_t)b * CIN * HW;

  const bool okT = (y0 > 0), okB = (y0 + 2 < H);
  const bool okL = (x0 > 0), okR = (x0 + CPT < W);
  const int xl = okL ? (x0 - 1) : 0;
  const int xr = okR ? (x0 + CPT) : 0;

  float acc[NC][2][CPT];
  #pragma unroll
  for (int u = 0; u < NC; ++u)
    #pragma unroll
    for (int o = 0; o < 2; ++o)
      #pragma unroll
      for (int q = 0; q < CPT; ++q) acc[u][o][q] = 0.f;

  #pragma unroll 1
  for (int ci = 0; ci < CIN; ++ci) {
    const float* p = ib + ci * HW;
    const float* wci = w + ((size_t)co0 * CIN + ci) * 9;
    #pragma unroll
    for (int r = 0; r < 4; ++r) {            // input rows y0-1+r
      const bool ok = (r == 0) ? okT : ((r == 3) ? okB : true);
      const int iy = ok ? (y0 - 1 + r) : 0;
      const float* row = p + iy * W;
      float v[CPT + 2];
      if (CPT == 4) {
        float  lf = row[xl];
        float4 m  = *(const float4*)(row + x0);
        float  rf = row[xr];
        v[0] = (ok && okL) ? lf : 0.f;
        v[1] = ok ? m.x : 0.f;
        v[2] = ok ? m.y : 0.f;
        v[3] = ok ? m.z : 0.f;
        v[4] = ok ? m.w : 0.f;
        v[5] = (ok && okR) ? rf : 0.f;
      } else if (CPT == 2) {
        float  lf = row[xl];
        float2 m  = *(const float2*)(row + x0);   // x0 even -> aligned
        float  rf = row[xr];
        v[0] = (ok && okL) ? lf : 0.f;
        v[1] = ok ? m.x : 0.f;
        v[2] = ok ? m.y : 0.f;
        v[3] = (ok && okR) ? rf : 0.f;
      } else {
        v[0] = (ok && okL) ? row[xl] : 0.f;
        #pragma unroll
        for (int q = 0; q < CPT; ++q) v[1 + q] = ok ? row[x0 + q] : 0.f;
        v[CPT + 1] = (ok && okR) ? row[xr] : 0.f;
      }
      // input row r -> out-row0 with wrow r (r<=2), out-row1 with wrow r-1 (r>=1)
      #pragma unroll
      for (int u = 0; u < NC; ++u) {
        const float* wp = wci + (size_t)u * CIN * 9;   // wave-uniform s_loads
        if (r <= 2) {
          const float w0 = wp[r * 3], w1 = wp[r * 3 + 1], w2 = wp[r * 3 + 2];
          #pragma unroll
          for (int q = 0; q < CPT; ++q)
            acc[u][0][q] += v[q] * w0 + v[q + 1] * w1 + v[q + 2] * w2;
        }
        if (r >= 1) {
          const float w0 = wp[(r-1) * 3], w1 = wp[(r-1) * 3 + 1], w2 = wp[(r-1) * 3 + 2];
          #pragma unroll
          for (int q = 0; q < CPT; ++q)
            acc[u][1][q] += v[q] * w0 + v[q + 1] * w1 + v[q + 2] * w2;
        }
      }
    }
  }

  #pragma unroll
  for (int u = 0; u < NC; ++u) {
    const float bv = bias[co0 + u];
    float* op = out + ((size_t)(b * Cout + co0 + u) * H + y0) * W + x0;
    #pragma unroll
    for (int o = 0; o < 2; ++o) {
      float* opo = op + o * W;
      if (CPT == 4) {
        float4 r4;
        r4.x = act_fn<ACT>(acc[u][o][0] + bv);
        r4.y = act_fn<ACT>(acc[u][o][1] + bv);
        r4.z = act_fn<ACT>(acc[u][o][2] + bv);
        r4.w = act_fn<ACT>(acc[u][o][3] + bv);
        *(float4*)opo = r4;
      } else if (CPT == 2) {
        float2 r2;
        r2.x = act_fn<ACT>(acc[u][o][0] + bv);
        r2.y = act_fn<ACT>(acc[u][o][1] + bv);
        *(float2*)opo = r2;
      } else {
        #pragma unroll
        for (int q = 0; q < CPT; ++q) opo[q] = act_fn<ACT>(acc[u][o][q] + bv);
      }
    }
  }
}

// ---------------- stride-1 3x3 SAME conv, 1 row (dec1 only) --------------------
template<int ACT, int NC, int CPT, int CIN>
__global__ __launch_bounds__(256)
void conv_s1(const float* __restrict__ in, const float* __restrict__ w,
             const float* __restrict__ bias, float* __restrict__ out,
             int Cout, int H, int W) {
  const int cogs = Cout / NC;
  const int gx  = blockIdx.x;
  const int cog = gx % cogs;
  const int b   = gx / cogs;
  const int co0 = cog * NC;
  const int Wq  = W / CPT;
  const int items = H * Wq;
  const int item  = blockIdx.y * 256 + threadIdx.x;
  if (item >= items) return;
  const int y  = item / Wq;
  const int x0 = (item - y * Wq) * CPT;

  const int HW = H * W;
  const float* ib = in + (size_t)b * CIN * HW;

  const bool okT = (y > 0), okB = (y < H - 1);
  const bool okL = (x0 > 0), okR = (x0 + CPT < W);
  const int ym = okT ? (y - 1) : 0;
  const int yp = okB ? (y + 1) : 0;
  const int xl = okL ? (x0 - 1) : 0;
  const int xr = okR ? (x0 + CPT) : 0;

  float acc[NC][CPT];
  #pragma unroll
  for (int u = 0; u < NC; ++u)
    #pragma unroll
    for (int q = 0; q < CPT; ++q) acc[u][q] = 0.f;

  #pragma unroll 2
  for (int ci = 0; ci < CIN; ++ci) {
    const float* p = ib + ci * HW;
    const float* wci = w + ((size_t)co0 * CIN + ci) * 9;
    #pragma unroll
    for (int dy = 0; dy < 3; ++dy) {
      const int  ry    = (dy == 0) ? ym : ((dy == 1) ? y : yp);
      const bool okRow = (dy == 0) ? okT : ((dy == 1) ? true : okB);
      const float* r = p + ry * W;
      float v[CPT + 2];
      if (CPT == 2) {
        float  lf = r[xl];
        float2 m  = *(const float2*)(r + x0);
        float  rf = r[xr];
        v[0] = (okRow && okL) ? lf : 0.f;
        v[1] = okRow ? m.x : 0.f;
        v[2] = okRow ? m.y : 0.f;
        v[3] = (okRow && okR) ? rf : 0.f;
      } else {
        v[0] = (okRow && okL) ? r[xl] : 0.f;
        #pragma unroll
        for (int q = 0; q < CPT; ++q) v[1 + q] = okRow ? r[x0 + q] : 0.f;
        v[CPT + 1] = (okRow && okR) ? r[xr] : 0.f;
      }
      #pragma unroll
      for (int u = 0; u < NC; ++u) {
        const float* wp = wci + u * CIN * 9 + dy * 3;
        const float w0 = wp[0], w1 = wp[1], w2 = wp[2];
        #pragma unroll
        for (int q = 0; q < CPT; ++q)
          acc[u][q] += v[q] * w0 + v[q + 1] * w1 + v[q + 2] * w2;
      }
    }
  }

  #pragma unroll
  for (int u = 0; u < NC; ++u) {
    const float bv = bias[co0 + u];
    float* op = out + ((size_t)(b * Cout + co0 + u) * H + y) * W + x0;
    if (CPT == 2) {
      float2 r2;
      r2.x = act_fn<ACT>(acc[u][0] + bv);
      r2.y = act_fn<ACT>(acc[u][1] + bv);
      *(float2*)op = r2;
    } else {
      #pragma unroll
      for (int q = 0; q < CPT; ++q) op[q] = act_fn<ACT>(acc[u][q] + bv);
    }
  }
}

// ---------------- stride-2 3x3 SAME conv (pad_before=0, pad_after=1) -----------
template<int ACT, int NC, int CPT, int CIN>
__global__ __launch_bounds__(256)
void conv_s2(const float* __restrict__ in, const float* __restrict__ w,
             const float* __restrict__ bias, float* __restrict__ out,
             int Cout, int H, int W) {
  const int Ho = H >> 1, Wo = W >> 1;
  const int cogs = Cout / NC;
  const int gx  = blockIdx.x;
  const int cog = gx % cogs;
  const int b   = gx / cogs;
  const int co0 = cog * NC;
  const int Wq  = Wo / CPT;
  const int items = Ho * Wq;
  const int item  = blockIdx.y * 256 + threadIdx.x;
  if (item >= items) return;
  const int y  = item / Wq;
  const int x0 = (item - y * Wq) * CPT;
  const int ix = 2 * x0;

  const int HW = H * W;
  const float* ib = in + (size_t)b * CIN * HW;

  const int iy0 = 2 * y, iy1 = 2 * y + 1, iy2 = 2 * y + 2;
  const bool okB = (iy2 < H);
  const int iy2c = okB ? iy2 : 0;
  const bool okR = (ix + 2 * CPT < W);
  const int ixr  = okR ? (ix + 2 * CPT) : 0;

  float acc[NC][CPT];
  #pragma unroll
  for (int u = 0; u < NC; ++u)
    #pragma unroll
    for (int q = 0; q < CPT; ++q) acc[u][q] = 0.f;

  #pragma unroll 2
  for (int ci = 0; ci < CIN; ++ci) {
    const float* p = ib + ci * HW;
    const float* wci = w + ((size_t)co0 * CIN + ci) * 9;
    #pragma unroll
    for (int dy = 0; dy < 3; ++dy) {
      const int  ry    = (dy == 0) ? iy0 : ((dy == 1) ? iy1 : iy2c);
      const bool okRow = (dy < 2) || okB;
      const float* r = p + ry * W;
      float v[2 * CPT + 1];
      if (CPT == 4) {
        float4 m0 = *(const float4*)(r + ix);
        float4 m1 = *(const float4*)(r + ix + 4);
        float  rf = r[ixr];
        v[0] = okRow ? m0.x : 0.f; v[1] = okRow ? m0.y : 0.f;
        v[2] = okRow ? m0.z : 0.f; v[3] = okRow ? m0.w : 0.f;
        v[4] = okRow ? m1.x : 0.f; v[5] = okRow ? m1.y : 0.f;
        v[6] = okRow ? m1.z : 0.f; v[7] = okRow ? m1.w : 0.f;
        v[8] = (okRow && okR) ? rf : 0.f;
      } else if (CPT == 2) {
        float4 m0 = *(const float4*)(r + ix);
        float  rf = r[ixr];
        v[0] = okRow ? m0.x : 0.f; v[1] = okRow ? m0.y : 0.f;
        v[2] = okRow ? m0.z : 0.f; v[3] = okRow ? m0.w : 0.f;
        v[4] = (okRow && okR) ? rf : 0.f;
      } else {
        float2 m0 = *(const float2*)(r + ix);
        float  rf = r[ixr];
        v[0] = okRow ? m0.x : 0.f; v[1] = okRow ? m0.y : 0.f;
        v[2] = (okRow && okR) ? rf : 0.f;
      }
      #pragma unroll
      for (int u = 0; u < NC; ++u) {
        const float* wp = wci + u * CIN * 9 + dy * 3;
        const float w0 = wp[0], w1 = wp[1], w2 = wp[2];
        #pragma unroll
        for (int q = 0; q < CPT; ++q)
          acc[u][q] += v[2*q] * w0 + v[2*q + 1] * w1 + v[2*q + 2] * w2;
      }
    }
  }

  #pragma unroll
  for (int u = 0; u < NC; ++u) {
    const float bv = bias[co0 + u];
    float* op = out + ((size_t)(b * Cout + co0 + u) * Ho + y) * Wo + x0;
    if (CPT == 4) {
      float4 r4;
      r4.x = act_fn<ACT>(acc[u][0] + bv);
      r4.y = act_fn<ACT>(acc[u][1] + bv);
      r4.z = act_fn<ACT>(acc[u][2] + bv);
      r4.w = act_fn<ACT>(acc[u][3] + bv);
      *(float4*)op = r4;
    } else if (CPT == 2) {
      float2 r2;
      r2.x = act_fn<ACT>(acc[u][0] + bv);
      r2.y = act_fn<ACT>(acc[u][1] + bv);
      *(float2*)op = r2;
    } else {
      #pragma unroll
      for (int q = 0; q < CPT; ++q) op[q] = act_fn<ACT>(acc[u][q] + bv);
    }
  }
}

// ---------------- stride-2 3x3 SAME transposed conv ----------------------------
// out[2i,2j]=xtl*w00+xtr*w02+xbl*w20+xbr*w22; out[2i,2j+1]=xtr*w01+xbr*w21
// out[2i+1,2j]=xbl*w10+xbr*w12;               out[2i+1,2j+1]=xbr*w11
template<int ACT, int NC, int CIN>
__global__ __launch_bounds__(256)
void tconv(const float* __restrict__ in, const float* __restrict__ w,
           const float* __restrict__ bias, float* __restrict__ out,
           int Cout, int Hin) {
  const int cogs = Cout / NC;
  const int gx  = blockIdx.x;
  const int cog = gx % cogs;
  const int b   = gx / cogs;
  const int co0 = cog * NC;
  const int items = Hin * Hin;
  const int item  = blockIdx.y * 256 + threadIdx.x;
  if (item >= items) return;
  const int i = item / Hin;
  const int j = item - i * Hin;

  const float* ib = in + (size_t)b * CIN * items;
  const bool okT = (i > 0), okL = (j > 0);
  const int im = okT ? i - 1 : 0;
  const int jm = okL ? j - 1 : 0;

  float a00[NC], a01[NC], a10[NC], a11[NC];
  #pragma unroll
  for (int u = 0; u < NC; ++u) { a00[u]=0.f; a01[u]=0.f; a10[u]=0.f; a11[u]=0.f; }

  #pragma unroll 2
  for (int ci = 0; ci < CIN; ++ci) {
    const float* p = ib + ci * items;
    float xtl = p[im*Hin + jm]; xtl = (okT && okL) ? xtl : 0.f;
    float xtr = p[im*Hin + j];  xtr = okT ? xtr : 0.f;
    float xbl = p[i*Hin + jm];  xbl = okL ? xbl : 0.f;
    float xbr = p[i*Hin + j];
    const float* wci = w + ((size_t)co0 * CIN + ci) * 9;
    #pragma unroll
    for (int u = 0; u < NC; ++u) {
      const float* wp = wci + u * CIN * 9;
      const float w00 = wp[0], w01 = wp[1], w02 = wp[2];
      const float w10 = wp[3], w11 = wp[4], w12 = wp[5];
      const float w20 = wp[6], w21 = wp[7], w22 = wp[8];
      a00[u] += xtl*w00 + xtr*w02 + xbl*w20 + xbr*w22;
      a01[u] += xtr*w01 + xbr*w21;
      a10[u] += xbl*w10 + xbr*w12;
      a11[u] += xbr*w11;
    }
  }

  const int Ho = Hin * 2;
  #pragma unroll
  for (int u = 0; u < NC; ++u) {
    const float bv = bias[co0 + u];
    float* op = out + (size_t)(b * Cout + co0 + u) * Ho * Ho + (2*i) * Ho + 2*j;
    float2 t0, t1;
    t0.x = act_fn<ACT>(a00[u] + bv); t0.y = act_fn<ACT>(a01[u] + bv);
    t1.x = act_fn<ACT>(a10[u] + bv); t1.y = act_fn<ACT>(a11[u] + bv);
    *(float2*)op = t0;
    *(float2*)(op + Ho) = t1;
  }
}

// ---------------- keypoint reductions: S = sum R, Sh = sum R*h, Sw = sum R*w ----
__global__ __launch_bounds__(64)
void kp_reduce(const float* __restrict__ R, float* __restrict__ S,
               float* __restrict__ Sh, float* __restrict__ Sw) {
  const int bk = blockIdx.x;       // b*K + k, 16x16 maps
  const int t = threadIdx.x;       // 64
  const float* p = R + (size_t)bk * 256;
  float s = 0.f, sh = 0.f, sw = 0.f;
  #pragma unroll
  for (int q = 0; q < 4; ++q) {
    int idx = t + q * 64;
    float v = p[idx];
    s  += v;
    sh += v * (float)(idx >> 4);
    sw += v * (float)(idx & 15);
  }
  #pragma unroll
  for (int off = 32; off > 0; off >>= 1) {
    s  += __shfl_down(s, off);
    sh += __shfl_down(sh, off);
    sw += __shfl_down(sw, off);
  }
  if (t == 0) { S[bk] = s; Sh[bk] = sh; Sw[bk] = sw; }
}

// ---------------- gaussian blob maps -------------------------------------------
__global__ __launch_bounds__(256)
void kp_maps(const float* __restrict__ S, const float* __restrict__ Sh,
             const float* __restrict__ Sw, float* __restrict__ maps, int K) {
  const int bk = blockIdx.x;
  const int b = bk / K;
  const int t = threadIdx.x;       // 256 = 16x16
  const float s   = S[bk];
  const float den = S[b * K + (K - 1)];
  const float mu  = s * (1.0f / 256.0f);
  const float c0  = Sh[bk] / den;
  const float c1  = Sw[bk] / den;
  const float u = (float)(t >> 4);
  const float v = (float)(t & 15);
  const float d2 = (u - c0) * (u - c0) + (v - c1) * (v - c1);
  maps[(size_t)bk * 256 + t] = mu * expf(-0.5f * d2);
}

extern "C" void kernel_launch(void* const* d_in, const int* in_sizes, int n_in,
                              void* d_out, int out_size, void* d_ws, size_t ws_size,
                              hipStream_t stream) {
  const int B = 32;  // 4 * 8
  const float* x = (const float*)d_in[0];
  const float* ew[7]; const float* eb[7];
  for (int j = 0; j < 7; ++j) { ew[j] = (const float*)d_in[1 + 2*j]; eb[j] = (const float*)d_in[2 + 2*j]; }
  const float* dw[6]; const float* db[6];
  for (int j = 0; j < 6; ++j) { dw[j] = (const float*)d_in[15 + 2*j]; db[j] = (const float*)d_in[16 + 2*j]; }

  float* ws   = (float*)d_ws;
  float* bufA = ws;                       // 32*32*128*128 = 16,777,216 floats
  float* bufB = bufA + 16777216;
  float* R    = bufB + 16777216;          // 32*128*256 = 1,048,576
  float* maps = R + 1048576;
  float* S    = maps + 1048576;           // 4096
  float* Sh   = S + 4096;
  float* Sw   = Sh + 4096;
  float* outp = (float*)d_out;            // 32*16*128*128

  dim3 blk(256);

  // ---- encoder ---- (R13 config; enc3 -> conv64_lds, single variable)
  conv_s1r2<ACT_ID,    8,4,3>  <<<dim3(B*4,   8), blk, 0, stream>>>(x,    ew[0], eb[0], bufA, 32,  128, 128); // 1024
  conv_s1r2<ACT_ID,    8,4,32> <<<dim3(B*4,   8), blk, 0, stream>>>(bufA, ew[1], eb[1], bufB, 32,  128, 128); // 1024
  conv_s2<ACT_LRELU,   8,4,32> <<<dim3(B*8,   4), blk, 0, stream>>>(bufB, ew[2], eb[2], bufA, 64,  128, 128); // 1024
  conv64_lds<ACT_LRELU,2,64>   <<<dim3(B*32),     blk, 0, stream>>>(bufA, ew[3], eb[3], bufB, 64);            // 1024
  conv_s2<ACT_LRELU,   8,2,64> <<<dim3(B*16,  2), blk, 0, stream>>>(bufB, ew[4], eb[4], bufA, 128, 64,  64);  // 1024
  conv32_lds<ACT_LRELU,4,128>  <<<dim3(B*32),     blk, 0, stream>>>(bufA, ew[5], eb[5], bufB, 128);           // 1024
  conv_s2<ACT_SOFTPLUS,4,1,128><<<dim3(B*32,  1), blk, 0, stream>>>(bufB, ew[6], eb[6], R,    128, 32,  32);  // 1024

  // ---- keypoint bottleneck ----
  kp_reduce<<<dim3(B*128), dim3(64), 0, stream>>>(R, S, Sh, Sw);
  kp_maps  <<<dim3(B*128), blk, 0, stream>>>(S, Sh, Sw, maps, 128);

  // ---- decoder ---- (exact R13)
  tconv<ACT_RELU,   2,128> <<<dim3(B*32,  1), blk, 0, stream>>>(maps, dw[0], db[0], bufA, 64, 16);            // 1024
  conv_s1<ACT_RELU, 4,2,64><<<dim3(B*16,  2), blk, 0, stream>>>(bufA, dw[1], db[1], bufB, 64, 32, 32);        // 1024
  tconv<ACT_RELU,   4,64>  <<<dim3(B*8,   4), blk, 0, stream>>>(bufB, dw[2], db[2], bufA, 32, 32);            // 1024
  conv_s1r2<ACT_RELU,4,2,32><<<dim3(B*8,  4), blk, 0, stream>>>(bufA, dw[3], db[3], bufB, 32, 64, 64);        // 1024
  tconv<ACT_RELU,   8,32>  <<<dim3(B*2,  16), blk, 0, stream>>>(bufB, dw[4], db[4], bufA, 16, 64);            // 1024
  conv_s1r2<ACT_RELU,4,4,16><<<dim3(B*4,  8), blk, 0, stream>>>(bufA, dw[5], db[5], outp, 16, 128, 128);      // 1024
}

// Round 14
// 1188.393 us; speedup vs baseline: 1.1168x; 1.1168x over previous
//
#include <hip/hip_runtime.h>
#include <math.h>

// ULOSD keypoint autoencoder, fp32 direct convolutions.
// Round 17: R16's conv64_lds rejected (322us: WRITE_SIZE 530MB = float4 g[4]
// prefetch spilled to scratch (R4 failure mode via 4x prefetch window) +
// 25.2M bank conflicts from stride-68 4*tc layout; VALUBusy 39%).
// Revert enc3 to R13 s1r2. One low-risk extension: dec1 (same 32^2 geometry
// as enc5's proven conv32_lds win) -> conv32_lds<RELU,2,64>, grid B*32=1024
// blocks (same wave supply as its conv_s1 form), single-float4 prefetch
// (proven register footprint). Loads/output 3 -> 1. Everything else == R13.

enum { ACT_ID = 0, ACT_LRELU = 1, ACT_SOFTPLUS = 2, ACT_RELU = 3 };

template<int ACT>
__device__ __forceinline__ float act_fn(float x) {
  if (ACT == ACT_LRELU)    return x >= 0.f ? x : 0.2f * x;
  if (ACT == ACT_SOFTPLUS) return fmaxf(x, 0.f) + log1pf(expf(-fabsf(x)));
  if (ACT == ACT_RELU)     return fmaxf(x, 0.f);
  return x;
}

// ---------------- 32x32 stride-1 conv, LDS plane-staged, 2x2 out per thread ----
template<int ACT, int NC, int CIN>
__global__ __launch_bounds__(256)
void conv32_lds(const float* __restrict__ in, const float* __restrict__ w,
                const float* __restrict__ bias, float* __restrict__ out,
                int Cout) {
  __shared__ float pl[2][32 * 36];
  const int cogs = Cout / NC;
  const int gx  = blockIdx.x;           // b*cogs + cog
  const int cog = gx % cogs;
  const int b   = gx / cogs;
  const int co0 = cog * NC;
  const int t   = threadIdx.x;
  const int x0  = (t & 15) * 2;         // output cols x0, x0+1
  const int y0  = (t >> 4) * 2;         // output rows y0, y0+1

  const float* ib = in + (size_t)b * CIN * 1024;
  const int lx = (t >> 3) * 36 + (t & 7) * 4;   // this thread's LDS stage slot

  {
    float4 g0 = *(const float4*)(ib + t * 4);
    *(float4*)&pl[0][lx] = g0;
  }
  __syncthreads();

  const bool okT = (y0 > 0), okB = (y0 + 2 < 32);
  const bool okL = (x0 > 0), okR = (x0 + 2 < 32);

  float acc[NC][2][2];
  #pragma unroll
  for (int u = 0; u < NC; ++u)
    #pragma unroll
    for (int o = 0; o < 2; ++o) { acc[u][o][0] = 0.f; acc[u][o][1] = 0.f; }

  int cur = 0;
  #pragma unroll 1
  for (int ci = 0; ci < CIN; ++ci) {
    const bool more = (ci + 1 < CIN);
    float4 g = {0.f, 0.f, 0.f, 0.f};
    if (more) g = *(const float4*)(ib + (size_t)(ci + 1) * 1024 + t * 4);

    const float* P = pl[cur];
    const float* wci = w + ((size_t)co0 * CIN + ci) * 9;
    #pragma unroll
    for (int r = 0; r < 4; ++r) {
      const bool ok = (r == 0) ? okT : ((r == 3) ? okB : true);
      const int ry = ok ? (y0 - 1 + r) : 0;
      const int base = ry * 36 + x0;
      float v[4];
      v[0] = (ok && okL) ? P[base - 1] : 0.f;
      v[1] = ok ? P[base]     : 0.f;
      v[2] = ok ? P[base + 1] : 0.f;
      v[3] = (ok && okR) ? P[base + 2] : 0.f;
      #pragma unroll
      for (int u = 0; u < NC; ++u) {
        const float* wp = wci + (size_t)u * CIN * 9;
        if (r <= 2) {
          const float w0 = wp[r * 3], w1 = wp[r * 3 + 1], w2 = wp[r * 3 + 2];
          acc[u][0][0] += v[0] * w0 + v[1] * w1 + v[2] * w2;
          acc[u][0][1] += v[1] * w0 + v[2] * w1 + v[3] * w2;
        }
        if (r >= 1) {
          const float w0 = wp[(r-1) * 3], w1 = wp[(r-1) * 3 + 1], w2 = wp[(r-1) * 3 + 2];
          acc[u][1][0] += v[0] * w0 + v[1] * w1 + v[2] * w2;
          acc[u][1][1] += v[1] * w0 + v[2] * w1 + v[3] * w2;
        }
      }
    }
    if (more) *(float4*)&pl[cur ^ 1][lx] = g;
    __syncthreads();
    cur ^= 1;
  }

  #pragma unroll
  for (int u = 0; u < NC; ++u) {
    const float bv = bias[co0 + u];
    float* op = out + ((size_t)(b * Cout + co0 + u) * 32 + y0) * 32 + x0;
    float2 r0, r1;
    r0.x = act_fn<ACT>(acc[u][0][0] + bv); r0.y = act_fn<ACT>(acc[u][0][1] + bv);
    r1.x = act_fn<ACT>(acc[u][1][0] + bv); r1.y = act_fn<ACT>(acc[u][1][1] + bv);
    *(float2*)op = r0;
    *(float2*)(op + 32) = r1;
  }
}

// ---------------- stride-1 3x3 SAME conv, 2 output rows x CPT cols, NC couts ---
template<int ACT, int NC, int CPT, int CIN>
__global__ __launch_bounds__(256)
void conv_s1r2(const float* __restrict__ in, const float* __restrict__ w,
               const float* __restrict__ bias, float* __restrict__ out,
               int Cout, int H, int W) {
  const int cogs = Cout / NC;
  const int gx  = blockIdx.x;           // b*cogs + cog
  const int cog = gx % cogs;
  const int b   = gx / cogs;
  const int co0 = cog * NC;
  const int Wq  = W / CPT;
  const int Hp  = H >> 1;               // row pairs
  const int items = Hp * Wq;
  const int item  = blockIdx.y * 256 + threadIdx.x;
  if (item >= items) return;
  const int yp = item / Wq;
  const int x0 = (item - yp * Wq) * CPT;
  const int y0 = 2 * yp;                // output rows y0, y0+1; input y0-1..y0+2

  const int HW = H * W;
  const float* ib = in + (size_t)b * CIN * HW;

  const bool okT = (y0 > 0), okB = (y0 + 2 < H);
  const bool okL = (x0 > 0), okR = (x0 + CPT < W);
  const int xl = okL ? (x0 - 1) : 0;
  const int xr = okR ? (x0 + CPT) : 0;

  float acc[NC][2][CPT];
  #pragma unroll
  for (int u = 0; u < NC; ++u)
    #pragma unroll
    for (int o = 0; o < 2; ++o)
      #pragma unroll
      for (int q = 0; q < CPT; ++q) acc[u][o][q] = 0.f;

  #pragma unroll 1
  for (int ci = 0; ci < CIN; ++ci) {
    const float* p = ib + ci * HW;
    const float* wci = w + ((size_t)co0 * CIN + ci) * 9;
    #pragma unroll
    for (int r = 0; r < 4; ++r) {            // input rows y0-1+r
      const bool ok = (r == 0) ? okT : ((r == 3) ? okB : true);
      const int iy = ok ? (y0 - 1 + r) : 0;
      const float* row = p + iy * W;
      float v[CPT + 2];
      if (CPT == 4) {
        float  lf = row[xl];
        float4 m  = *(const float4*)(row + x0);
        float  rf = row[xr];
        v[0] = (ok && okL) ? lf : 0.f;
        v[1] = ok ? m.x : 0.f;
        v[2] = ok ? m.y : 0.f;
        v[3] = ok ? m.z : 0.f;
        v[4] = ok ? m.w : 0.f;
        v[5] = (ok && okR) ? rf : 0.f;
      } else if (CPT == 2) {
        float  lf = row[xl];
        float2 m  = *(const float2*)(row + x0);   // x0 even -> aligned
        float  rf = row[xr];
        v[0] = (ok && okL) ? lf : 0.f;
        v[1] = ok ? m.x : 0.f;
        v[2] = ok ? m.y : 0.f;
        v[3] = (ok && okR) ? rf : 0.f;
      } else {
        v[0] = (ok && okL) ? row[xl] : 0.f;
        #pragma unroll
        for (int q = 0; q < CPT; ++q) v[1 + q] = ok ? row[x0 + q] : 0.f;
        v[CPT + 1] = (ok && okR) ? row[xr] : 0.f;
      }
      // input row r -> out-row0 with wrow r (r<=2), out-row1 with wrow r-1 (r>=1)
      #pragma unroll
      for (int u = 0; u < NC; ++u) {
        const float* wp = wci + (size_t)u * CIN * 9;   // wave-uniform s_loads
        if (r <= 2) {
          const float w0 = wp[r * 3], w1 = wp[r * 3 + 1], w2 = wp[r * 3 + 2];
          #pragma unroll
          for (int q = 0; q < CPT; ++q)
            acc[u][0][q] += v[q] * w0 + v[q + 1] * w1 + v[q + 2] * w2;
        }
        if (r >= 1) {
          const float w0 = wp[(r-1) * 3], w1 = wp[(r-1) * 3 + 1], w2 = wp[(r-1) * 3 + 2];
          #pragma unroll
          for (int q = 0; q < CPT; ++q)
            acc[u][1][q] += v[q] * w0 + v[q + 1] * w1 + v[q + 2] * w2;
        }
      }
    }
  }

  #pragma unroll
  for (int u = 0; u < NC; ++u) {
    const float bv = bias[co0 + u];
    float* op = out + ((size_t)(b * Cout + co0 + u) * H + y0) * W + x0;
    #pragma unroll
    for (int o = 0; o < 2; ++o) {
      float* opo = op + o * W;
      if (CPT == 4) {
        float4 r4;
        r4.x = act_fn<ACT>(acc[u][o][0] + bv);
        r4.y = act_fn<ACT>(acc[u][o][1] + bv);
        r4.z = act_fn<ACT>(acc[u][o][2] + bv);
        r4.w = act_fn<ACT>(acc[u][o][3] + bv);
        *(float4*)opo = r4;
      } else if (CPT == 2) {
        float2 r2;
        r2.x = act_fn<ACT>(acc[u][o][0] + bv);
        r2.y = act_fn<ACT>(acc[u][o][1] + bv);
        *(float2*)opo = r2;
      } else {
        #pragma unroll
        for (int q = 0; q < CPT; ++q) opo[q] = act_fn<ACT>(acc[u][o][q] + bv);
      }
    }
  }
}

// ---------------- stride-2 3x3 SAME conv (pad_before=0, pad_after=1) -----------
template<int ACT, int NC, int CPT, int CIN>
__global__ __launch_bounds__(256)
void conv_s2(const float* __restrict__ in, const float* __restrict__ w,
             const float* __restrict__ bias, float* __restrict__ out,
             int Cout, int H, int W) {
  const int Ho = H >> 1, Wo = W >> 1;
  const int cogs = Cout / NC;
  const int gx  = blockIdx.x;
  const int cog = gx % cogs;
  const int b   = gx / cogs;
  const int co0 = cog * NC;
  const int Wq  = Wo / CPT;
  const int items = Ho * Wq;
  const int item  = blockIdx.y * 256 + threadIdx.x;
  if (item >= items) return;
  const int y  = item / Wq;
  const int x0 = (item - y * Wq) * CPT;
  const int ix = 2 * x0;

  const int HW = H * W;
  const float* ib = in + (size_t)b * CIN * HW;

  const int iy0 = 2 * y, iy1 = 2 * y + 1, iy2 = 2 * y + 2;
  const bool okB = (iy2 < H);
  const int iy2c = okB ? iy2 : 0;
  const bool okR = (ix + 2 * CPT < W);
  const int ixr  = okR ? (ix + 2 * CPT) : 0;

  float acc[NC][CPT];
  #pragma unroll
  for (int u = 0; u < NC; ++u)
    #pragma unroll
    for (int q = 0; q < CPT; ++q) acc[u][q] = 0.f;

  #pragma unroll 2
  for (int ci = 0; ci < CIN; ++ci) {
    const float* p = ib + ci * HW;
    const float* wci = w + ((size_t)co0 * CIN + ci) * 9;
    #pragma unroll
    for (int dy = 0; dy < 3; ++dy) {
      const int  ry    = (dy == 0) ? iy0 : ((dy == 1) ? iy1 : iy2c);
      const bool okRow = (dy < 2) || okB;
      const float* r = p + ry * W;
      float v[2 * CPT + 1];
      if (CPT == 4) {
        float4 m0 = *(const float4*)(r + ix);
        float4 m1 = *(const float4*)(r + ix + 4);
        float  rf = r[ixr];
        v[0] = okRow ? m0.x : 0.f; v[1] = okRow ? m0.y : 0.f;
        v[2] = okRow ? m0.z : 0.f; v[3] = okRow ? m0.w : 0.f;
        v[4] = okRow ? m1.x : 0.f; v[5] = okRow ? m1.y : 0.f;
        v[6] = okRow ? m1.z : 0.f; v[7] = okRow ? m1.w : 0.f;
        v[8] = (okRow && okR) ? rf : 0.f;
      } else if (CPT == 2) {
        float4 m0 = *(const float4*)(r + ix);
        float  rf = r[ixr];
        v[0] = okRow ? m0.x : 0.f; v[1] = okRow ? m0.y : 0.f;
        v[2] = okRow ? m0.z : 0.f; v[3] = okRow ? m0.w : 0.f;
        v[4] = (okRow && okR) ? rf : 0.f;
      } else {
        float2 m0 = *(const float2*)(r + ix);
        float  rf = r[ixr];
        v[0] = okRow ? m0.x : 0.f; v[1] = okRow ? m0.y : 0.f;
        v[2] = (okRow && okR) ? rf : 0.f;
      }
      #pragma unroll
      for (int u = 0; u < NC; ++u) {
        const float* wp = wci + u * CIN * 9 + dy * 3;
        const float w0 = wp[0], w1 = wp[1], w2 = wp[2];
        #pragma unroll
        for (int q = 0; q < CPT; ++q)
          acc[u][q] += v[2*q] * w0 + v[2*q + 1] * w1 + v[2*q + 2] * w2;
      }
    }
  }

  #pragma unroll
  for (int u = 0; u < NC; ++u) {
    const float bv = bias[co0 + u];
    float* op = out + ((size_t)(b * Cout + co0 + u) * Ho + y) * Wo + x0;
    if (CPT == 4) {
      float4 r4;
      r4.x = act_fn<ACT>(acc[u][0] + bv);
      r4.y = act_fn<ACT>(acc[u][1] + bv);
      r4.z = act_fn<ACT>(acc[u][2] + bv);
      r4.w = act_fn<ACT>(acc[u][3] + bv);
      *(float4*)op = r4;
    } else if (CPT == 2) {
      float2 r2;
      r2.x = act_fn<ACT>(acc[u][0] + bv);
      r2.y = act_fn<ACT>(acc[u][1] + bv);
      *(float2*)op = r2;
    } else {
      #pragma unroll
      for (int q = 0; q < CPT; ++q) op[q] = act_fn<ACT>(acc[u][q] + bv);
    }
  }
}

// ---------------- stride-2 3x3 SAME transposed conv ----------------------------
// out[2i,2j]=xtl*w00+xtr*w02+xbl*w20+xbr*w22; out[2i,2j+1]=xtr*w01+xbr*w21
// out[2i+1,2j]=xbl*w10+xbr*w12;               out[2i+1,2j+1]=xbr*w11
template<int ACT, int NC, int CIN>
__global__ __launch_bounds__(256)
void tconv(const float* __restrict__ in, const float* __restrict__ w,
           const float* __restrict__ bias, float* __restrict__ out,
           int Cout, int Hin) {
  const int cogs = Cout / NC;
  const int gx  = blockIdx.x;
  const int cog = gx % cogs;
  const int b   = gx / cogs;
  const int co0 = cog * NC;
  const int items = Hin * Hin;
  const int item  = blockIdx.y * 256 + threadIdx.x;
  if (item >= items) return;
  const int i = item / Hin;
  const int j = item - i * Hin;

  const float* ib = in + (size_t)b * CIN * items;
  const bool okT = (i > 0), okL = (j > 0);
  const int im = okT ? i - 1 : 0;
  const int jm = okL ? j - 1 : 0;

  float a00[NC], a01[NC], a10[NC], a11[NC];
  #pragma unroll
  for (int u = 0; u < NC; ++u) { a00[u]=0.f; a01[u]=0.f; a10[u]=0.f; a11[u]=0.f; }

  #pragma unroll 2
  for (int ci = 0; ci < CIN; ++ci) {
    const float* p = ib + ci * items;
    float xtl = p[im*Hin + jm]; xtl = (okT && okL) ? xtl : 0.f;
    float xtr = p[im*Hin + j];  xtr = okT ? xtr : 0.f;
    float xbl = p[i*Hin + jm];  xbl = okL ? xbl : 0.f;
    float xbr = p[i*Hin + j];
    const float* wci = w + ((size_t)co0 * CIN + ci) * 9;
    #pragma unroll
    for (int u = 0; u < NC; ++u) {
      const float* wp = wci + u * CIN * 9;
      const float w00 = wp[0], w01 = wp[1], w02 = wp[2];
      const float w10 = wp[3], w11 = wp[4], w12 = wp[5];
      const float w20 = wp[6], w21 = wp[7], w22 = wp[8];
      a00[u] += xtl*w00 + xtr*w02 + xbl*w20 + xbr*w22;
      a01[u] += xtr*w01 + xbr*w21;
      a10[u] += xbl*w10 + xbr*w12;
      a11[u] += xbr*w11;
    }
  }

  const int Ho = Hin * 2;
  #pragma unroll
  for (int u = 0; u < NC; ++u) {
    const float bv = bias[co0 + u];
    float* op = out + (size_t)(b * Cout + co0 + u) * Ho * Ho + (2*i) * Ho + 2*j;
    float2 t0, t1;
    t0.x = act_fn<ACT>(a00[u] + bv); t0.y = act_fn<ACT>(a01[u] + bv);
    t1.x = act_fn<ACT>(a10[u] + bv); t1.y = act_fn<ACT>(a11[u] + bv);
    *(float2*)op = t0;
    *(float2*)(op + Ho) = t1;
  }
}

// ---------------- keypoint reductions: S = sum R, Sh = sum R*h, Sw = sum R*w ----
__global__ __launch_bounds__(64)
void kp_reduce(const float* __restrict__ R, float* __restrict__ S,
               float* __restrict__ Sh, float* __restrict__ Sw) {
  const int bk = blockIdx.x;       // b*K + k, 16x16 maps
  const int t = threadIdx.x;       // 64
  const float* p = R + (size_t)bk * 256;
  float s = 0.f, sh = 0.f, sw = 0.f;
  #pragma unroll
  for (int q = 0; q < 4; ++q) {
    int idx = t + q * 64;
    float v = p[idx];
    s  += v;
    sh += v * (float)(idx >> 4);
    sw += v * (float)(idx & 15);
  }
  #pragma unroll
  for (int off = 32; off > 0; off >>= 1) {
    s  += __shfl_down(s, off);
    sh += __shfl_down(sh, off);
    sw += __shfl_down(sw, off);
  }
  if (t == 0) { S[bk] = s; Sh[bk] = sh; Sw[bk] = sw; }
}

// ---------------- gaussian blob maps -------------------------------------------
__global__ __launch_bounds__(256)
void kp_maps(const float* __restrict__ S, const float* __restrict__ Sh,
             const float* __restrict__ Sw, float* __restrict__ maps, int K) {
  const int bk = blockIdx.x;
  const int b = bk / K;
  const int t = threadIdx.x;       // 256 = 16x16
  const float s   = S[bk];
  const float den = S[b * K + (K - 1)];
  const float mu  = s * (1.0f / 256.0f);
  const float c0  = Sh[bk] / den;
  const float c1  = Sw[bk] / den;
  const float u = (float)(t >> 4);
  const float v = (float)(t & 15);
  const float d2 = (u - c0) * (u - c0) + (v - c1) * (v - c1);
  maps[(size_t)bk * 256 + t] = mu * expf(-0.5f * d2);
}

extern "C" void kernel_launch(void* const* d_in, const int* in_sizes, int n_in,
                              void* d_out, int out_size, void* d_ws, size_t ws_size,
                              hipStream_t stream) {
  const int B = 32;  // 4 * 8
  const float* x = (const float*)d_in[0];
  const float* ew[7]; const float* eb[7];
  for (int j = 0; j < 7; ++j) { ew[j] = (const float*)d_in[1 + 2*j]; eb[j] = (const float*)d_in[2 + 2*j]; }
  const float* dw[6]; const float* db[6];
  for (int j = 0; j < 6; ++j) { dw[j] = (const float*)d_in[15 + 2*j]; db[j] = (const float*)d_in[16 + 2*j]; }

  float* ws   = (float*)d_ws;
  float* bufA = ws;                       // 32*32*128*128 = 16,777,216 floats
  float* bufB = bufA + 16777216;
  float* R    = bufB + 16777216;          // 32*128*256 = 1,048,576
  float* maps = R + 1048576;
  float* S    = maps + 1048576;           // 4096
  float* Sh   = S + 4096;
  float* Sw   = Sh + 4096;
  float* outp = (float*)d_out;            // 32*16*128*128

  dim3 blk(256);

  // ---- encoder ---- (exact R13)
  conv_s1r2<ACT_ID,    8,4,3>  <<<dim3(B*4,   8), blk, 0, stream>>>(x,    ew[0], eb[0], bufA, 32,  128, 128); // 1024
  conv_s1r2<ACT_ID,    8,4,32> <<<dim3(B*4,   8), blk, 0, stream>>>(bufA, ew[1], eb[1], bufB, 32,  128, 128); // 1024
  conv_s2<ACT_LRELU,   8,4,32> <<<dim3(B*8,   4), blk, 0, stream>>>(bufB, ew[2], eb[2], bufA, 64,  128, 128); // 1024
  conv_s1r2<ACT_LRELU, 4,4,64> <<<dim3(B*16,  2), blk, 0, stream>>>(bufA, ew[3], eb[3], bufB, 64,  64,  64);  // 1024
  conv_s2<ACT_LRELU,   8,2,64> <<<dim3(B*16,  2), blk, 0, stream>>>(bufB, ew[4], eb[4], bufA, 128, 64,  64);  // 1024
  conv32_lds<ACT_LRELU,4,128>  <<<dim3(B*32),     blk, 0, stream>>>(bufA, ew[5], eb[5], bufB, 128);           // 1024
  conv_s2<ACT_SOFTPLUS,4,1,128><<<dim3(B*32,  1), blk, 0, stream>>>(bufB, ew[6], eb[6], R,    128, 32,  32);  // 1024

  // ---- keypoint bottleneck ----
  kp_reduce<<<dim3(B*128), dim3(64), 0, stream>>>(R, S, Sh, Sw);
  kp_maps  <<<dim3(B*128), blk, 0, stream>>>(S, Sh, Sw, maps, 128);

  // ---- decoder ---- (R13 + dec1 -> conv32_lds<RELU,2,64>, 1024 blocks)
  tconv<ACT_RELU,   2,128> <<<dim3(B*32,  1), blk, 0, stream>>>(maps, dw[0], db[0], bufA, 64, 16);            // 1024
  conv32_lds<ACT_RELU,2,64><<<dim3(B*32),     blk, 0, stream>>>(bufA, dw[1], db[1], bufB, 64);                // 1024
  tconv<ACT_RELU,   4,64>  <<<dim3(B*8,   4), blk, 0, stream>>>(bufB, dw[2], db[2], bufA, 32, 32);            // 1024
  conv_s1r2<ACT_RELU,4,2,32><<<dim3(B*8,  4), blk, 0, stream>>>(bufA, dw[3], db[3], bufB, 32, 64, 64);        // 1024
  tconv<ACT_RELU,   8,32>  <<<dim3(B*2,  16), blk, 0, stream>>>(bufB, dw[4], db[4], bufA, 16, 64);            // 1024
  conv_s1r2<ACT_RELU,4,4,16><<<dim3(B*4,  8), blk, 0, stream>>>(bufA, dw[5], db[5], outp, 16, 128, 128);      // 1024
}

// Round 16
// 1157.917 us; speedup vs baseline: 1.1462x; 1.0263x over previous
//
#include <hip/hip_runtime.h>
#include <math.h>

// ULOSD keypoint autoencoder, fp32 direct convolutions.
// Round 19 == round 18 resubmitted (round-18 bench died on container
// acquisition; kernel never ran). R17 = 1188us best. Single variable vs R17:
// enc0 (CIN=3) -> conv_s1r2f with FULL ci unroll. enc0's unroll-1 loop pays
// one exposed ~400cy VMEM latency per 1152cy of FMA, x3; full unroll batches
// all 36 loads under 3456 FMA-cycles with ~36 transient regs (no pin, no
// persistent arrays -- distinct from R4's failure). Everything else == R17.

enum { ACT_ID = 0, ACT_LRELU = 1, ACT_SOFTPLUS = 2, ACT_RELU = 3 };

template<int ACT>
__device__ __forceinline__ float act_fn(float x) {
  if (ACT == ACT_LRELU)    return x >= 0.f ? x : 0.2f * x;
  if (ACT == ACT_SOFTPLUS) return fmaxf(x, 0.f) + log1pf(expf(-fabsf(x)));
  if (ACT == ACT_RELU)     return fmaxf(x, 0.f);
  return x;
}

// ---------------- 32x32 stride-1 conv, LDS plane-staged, 2x2 out per thread ----
template<int ACT, int NC, int CIN>
__global__ __launch_bounds__(256)
void conv32_lds(const float* __restrict__ in, const float* __restrict__ w,
                const float* __restrict__ bias, float* __restrict__ out,
                int Cout) {
  __shared__ float pl[2][32 * 36];
  const int cogs = Cout / NC;
  const int gx  = blockIdx.x;           // b*cogs + cog
  const int cog = gx % cogs;
  const int b   = gx / cogs;
  const int co0 = cog * NC;
  const int t   = threadIdx.x;
  const int x0  = (t & 15) * 2;         // output cols x0, x0+1
  const int y0  = (t >> 4) * 2;         // output rows y0, y0+1

  const float* ib = in + (size_t)b * CIN * 1024;
  const int lx = (t >> 3) * 36 + (t & 7) * 4;   // this thread's LDS stage slot

  {
    float4 g0 = *(const float4*)(ib + t * 4);
    *(float4*)&pl[0][lx] = g0;
  }
  __syncthreads();

  const bool okT = (y0 > 0), okB = (y0 + 2 < 32);
  const bool okL = (x0 > 0), okR = (x0 + 2 < 32);

  float acc[NC][2][2];
  #pragma unroll
  for (int u = 0; u < NC; ++u)
    #pragma unroll
    for (int o = 0; o < 2; ++o) { acc[u][o][0] = 0.f; acc[u][o][1] = 0.f; }

  int cur = 0;
  #pragma unroll 1
  for (int ci = 0; ci < CIN; ++ci) {
    const bool more = (ci + 1 < CIN);
    float4 g = {0.f, 0.f, 0.f, 0.f};
    if (more) g = *(const float4*)(ib + (size_t)(ci + 1) * 1024 + t * 4);

    const float* P = pl[cur];
    const float* wci = w + ((size_t)co0 * CIN + ci) * 9;
    #pragma unroll
    for (int r = 0; r < 4; ++r) {
      const bool ok = (r == 0) ? okT : ((r == 3) ? okB : true);
      const int ry = ok ? (y0 - 1 + r) : 0;
      const int base = ry * 36 + x0;
      float v[4];
      v[0] = (ok && okL) ? P[base - 1] : 0.f;
      v[1] = ok ? P[base]     : 0.f;
      v[2] = ok ? P[base + 1] : 0.f;
      v[3] = (ok && okR) ? P[base + 2] : 0.f;
      #pragma unroll
      for (int u = 0; u < NC; ++u) {
        const float* wp = wci + (size_t)u * CIN * 9;
        if (r <= 2) {
          const float w0 = wp[r * 3], w1 = wp[r * 3 + 1], w2 = wp[r * 3 + 2];
          acc[u][0][0] += v[0] * w0 + v[1] * w1 + v[2] * w2;
          acc[u][0][1] += v[1] * w0 + v[2] * w1 + v[3] * w2;
        }
        if (r >= 1) {
          const float w0 = wp[(r-1) * 3], w1 = wp[(r-1) * 3 + 1], w2 = wp[(r-1) * 3 + 2];
          acc[u][1][0] += v[0] * w0 + v[1] * w1 + v[2] * w2;
          acc[u][1][1] += v[1] * w0 + v[2] * w1 + v[3] * w2;
        }
      }
    }
    if (more) *(float4*)&pl[cur ^ 1][lx] = g;
    __syncthreads();
    cur ^= 1;
  }

  #pragma unroll
  for (int u = 0; u < NC; ++u) {
    const float bv = bias[co0 + u];
    float* op = out + ((size_t)(b * Cout + co0 + u) * 32 + y0) * 32 + x0;
    float2 r0, r1;
    r0.x = act_fn<ACT>(acc[u][0][0] + bv); r0.y = act_fn<ACT>(acc[u][0][1] + bv);
    r1.x = act_fn<ACT>(acc[u][1][0] + bv); r1.y = act_fn<ACT>(acc[u][1][1] + bv);
    *(float2*)op = r0;
    *(float2*)(op + 32) = r1;
  }
}

// ---------------- stride-1 3x3 SAME conv, 2 output rows x CPT cols, NC couts ---
template<int ACT, int NC, int CPT, int CIN>
__global__ __launch_bounds__(256)
void conv_s1r2(const float* __restrict__ in, const float* __restrict__ w,
               const float* __restrict__ bias, float* __restrict__ out,
               int Cout, int H, int W) {
  const int cogs = Cout / NC;
  const int gx  = blockIdx.x;           // b*cogs + cog
  const int cog = gx % cogs;
  const int b   = gx / cogs;
  const int co0 = cog * NC;
  const int Wq  = W / CPT;
  const int Hp  = H >> 1;               // row pairs
  const int items = Hp * Wq;
  const int item  = blockIdx.y * 256 + threadIdx.x;
  if (item >= items) return;
  const int yp = item / Wq;
  const int x0 = (item - yp * Wq) * CPT;
  const int y0 = 2 * yp;                // output rows y0, y0+1; input y0-1..y0+2

  const int HW = H * W;
  const float* ib = in + (size_t)b * CIN * HW;

  const bool okT = (y0 > 0), okB = (y0 + 2 < H);
  const bool okL = (x0 > 0), okR = (x0 + CPT < W);
  const int xl = okL ? (x0 - 1) : 0;
  const int xr = okR ? (x0 + CPT) : 0;

  float acc[NC][2][CPT];
  #pragma unroll
  for (int u = 0; u < NC; ++u)
    #pragma unroll
    for (int o = 0; o < 2; ++o)
      #pragma unroll
      for (int q = 0; q < CPT; ++q) acc[u][o][q] = 0.f;

  #pragma unroll 1
  for (int ci = 0; ci < CIN; ++ci) {
    const float* p = ib + ci * HW;
    const float* wci = w + ((size_t)co0 * CIN + ci) * 9;
    #pragma unroll
    for (int r = 0; r < 4; ++r) {            // input rows y0-1+r
      const bool ok = (r == 0) ? okT : ((r == 3) ? okB : true);
      const int iy = ok ? (y0 - 1 + r) : 0;
      const float* row = p + iy * W;
      float v[CPT + 2];
      if (CPT == 4) {
        float  lf = row[xl];
        float4 m  = *(const float4*)(row + x0);
        float  rf = row[xr];
        v[0] = (ok && okL) ? lf : 0.f;
        v[1] = ok ? m.x : 0.f;
        v[2] = ok ? m.y : 0.f;
        v[3] = ok ? m.z : 0.f;
        v[4] = ok ? m.w : 0.f;
        v[5] = (ok && okR) ? rf : 0.f;
      } else if (CPT == 2) {
        float  lf = row[xl];
        float2 m  = *(const float2*)(row + x0);   // x0 even -> aligned
        float  rf = row[xr];
        v[0] = (ok && okL) ? lf : 0.f;
        v[1] = ok ? m.x : 0.f;
        v[2] = ok ? m.y : 0.f;
        v[3] = (ok && okR) ? rf : 0.f;
      } else {
        v[0] = (ok && okL) ? row[xl] : 0.f;
        #pragma unroll
        for (int q = 0; q < CPT; ++q) v[1 + q] = ok ? row[x0 + q] : 0.f;
        v[CPT + 1] = (ok && okR) ? row[xr] : 0.f;
      }
      // input row r -> out-row0 with wrow r (r<=2), out-row1 with wrow r-1 (r>=1)
      #pragma unroll
      for (int u = 0; u < NC; ++u) {
        const float* wp = wci + (size_t)u * CIN * 9;   // wave-uniform s_loads
        if (r <= 2) {
          const float w0 = wp[r * 3], w1 = wp[r * 3 + 1], w2 = wp[r * 3 + 2];
          #pragma unroll
          for (int q = 0; q < CPT; ++q)
            acc[u][0][q] += v[q] * w0 + v[q + 1] * w1 + v[q + 2] * w2;
        }
        if (r >= 1) {
          const float w0 = wp[(r-1) * 3], w1 = wp[(r-1) * 3 + 1], w2 = wp[(r-1) * 3 + 2];
          #pragma unroll
          for (int q = 0; q < CPT; ++q)
            acc[u][1][q] += v[q] * w0 + v[q + 1] * w1 + v[q + 2] * w2;
        }
      }
    }
  }

  #pragma unroll
  for (int u = 0; u < NC; ++u) {
    const float bv = bias[co0 + u];
    float* op = out + ((size_t)(b * Cout + co0 + u) * H + y0) * W + x0;
    #pragma unroll
    for (int o = 0; o < 2; ++o) {
      float* opo = op + o * W;
      if (CPT == 4) {
        float4 r4;
        r4.x = act_fn<ACT>(acc[u][o][0] + bv);
        r4.y = act_fn<ACT>(acc[u][o][1] + bv);
        r4.z = act_fn<ACT>(acc[u][o][2] + bv);
        r4.w = act_fn<ACT>(acc[u][o][3] + bv);
        *(float4*)opo = r4;
      } else if (CPT == 2) {
        float2 r2;
        r2.x = act_fn<ACT>(acc[u][o][0] + bv);
        r2.y = act_fn<ACT>(acc[u][o][1] + bv);
        *(float2*)opo = r2;
      } else {
        #pragma unroll
        for (int q = 0; q < CPT; ++q) opo[q] = act_fn<ACT>(acc[u][o][q] + bv);
      }
    }
  }
}

// ---------------- same kernel, FULL ci unroll (small-CIN layers: enc0) ---------
template<int ACT, int NC, int CPT, int CIN>
__global__ __launch_bounds__(256)
void conv_s1r2f(const float* __restrict__ in, const float* __restrict__ w,
                const float* __restrict__ bias, float* __restrict__ out,
                int Cout, int H, int W) {
  const int cogs = Cout / NC;
  const int gx  = blockIdx.x;
  const int cog = gx % cogs;
  const int b   = gx / cogs;
  const int co0 = cog * NC;
  const int Wq  = W / CPT;
  const int Hp  = H >> 1;
  const int items = Hp * Wq;
  const int item  = blockIdx.y * 256 + threadIdx.x;
  if (item >= items) return;
  const int yp = item / Wq;
  const int x0 = (item - yp * Wq) * CPT;
  const int y0 = 2 * yp;

  const int HW = H * W;
  const float* ib = in + (size_t)b * CIN * HW;

  const bool okT = (y0 > 0), okB = (y0 + 2 < H);
  const bool okL = (x0 > 0), okR = (x0 + CPT < W);
  const int xl = okL ? (x0 - 1) : 0;
  const int xr = okR ? (x0 + CPT) : 0;

  float acc[NC][2][CPT];
  #pragma unroll
  for (int u = 0; u < NC; ++u)
    #pragma unroll
    for (int o = 0; o < 2; ++o)
      #pragma unroll
      for (int q = 0; q < CPT; ++q) acc[u][o][q] = 0.f;

  #pragma unroll
  for (int ci = 0; ci < CIN; ++ci) {
    const float* p = ib + ci * HW;
    const float* wci = w + ((size_t)co0 * CIN + ci) * 9;
    #pragma unroll
    for (int r = 0; r < 4; ++r) {
      const bool ok = (r == 0) ? okT : ((r == 3) ? okB : true);
      const int iy = ok ? (y0 - 1 + r) : 0;
      const float* row = p + iy * W;
      float v[CPT + 2];
      if (CPT == 4) {
        float  lf = row[xl];
        float4 m  = *(const float4*)(row + x0);
        float  rf = row[xr];
        v[0] = (ok && okL) ? lf : 0.f;
        v[1] = ok ? m.x : 0.f;
        v[2] = ok ? m.y : 0.f;
        v[3] = ok ? m.z : 0.f;
        v[4] = ok ? m.w : 0.f;
        v[5] = (ok && okR) ? rf : 0.f;
      } else if (CPT == 2) {
        float  lf = row[xl];
        float2 m  = *(const float2*)(row + x0);
        float  rf = row[xr];
        v[0] = (ok && okL) ? lf : 0.f;
        v[1] = ok ? m.x : 0.f;
        v[2] = ok ? m.y : 0.f;
        v[3] = (ok && okR) ? rf : 0.f;
      } else {
        v[0] = (ok && okL) ? row[xl] : 0.f;
        #pragma unroll
        for (int q = 0; q < CPT; ++q) v[1 + q] = ok ? row[x0 + q] : 0.f;
        v[CPT + 1] = (ok && okR) ? row[xr] : 0.f;
      }
      #pragma unroll
      for (int u = 0; u < NC; ++u) {
        const float* wp = wci + (size_t)u * CIN * 9;
        if (r <= 2) {
          const float w0 = wp[r * 3], w1 = wp[r * 3 + 1], w2 = wp[r * 3 + 2];
          #pragma unroll
          for (int q = 0; q < CPT; ++q)
            acc[u][0][q] += v[q] * w0 + v[q + 1] * w1 + v[q + 2] * w2;
        }
        if (r >= 1) {
          const float w0 = wp[(r-1) * 3], w1 = wp[(r-1) * 3 + 1], w2 = wp[(r-1) * 3 + 2];
          #pragma unroll
          for (int q = 0; q < CPT; ++q)
            acc[u][1][q] += v[q] * w0 + v[q + 1] * w1 + v[q + 2] * w2;
        }
      }
    }
  }

  #pragma unroll
  for (int u = 0; u < NC; ++u) {
    const float bv = bias[co0 + u];
    float* op = out + ((size_t)(b * Cout + co0 + u) * H + y0) * W + x0;
    #pragma unroll
    for (int o = 0; o < 2; ++o) {
      float* opo = op + o * W;
      if (CPT == 4) {
        float4 r4;
        r4.x = act_fn<ACT>(acc[u][o][0] + bv);
        r4.y = act_fn<ACT>(acc[u][o][1] + bv);
        r4.z = act_fn<ACT>(acc[u][o][2] + bv);
        r4.w = act_fn<ACT>(acc[u][o][3] + bv);
        *(float4*)opo = r4;
      } else if (CPT == 2) {
        float2 r2;
        r2.x = act_fn<ACT>(acc[u][o][0] + bv);
        r2.y = act_fn<ACT>(acc[u][o][1] + bv);
        *(float2*)opo = r2;
      } else {
        #pragma unroll
        for (int q = 0; q < CPT; ++q) opo[q] = act_fn<ACT>(acc[u][o][q] + bv);
      }
    }
  }
}

// ---------------- stride-2 3x3 SAME conv (pad_before=0, pad_after=1) -----------
template<int ACT, int NC, int CPT, int CIN>
__global__ __launch_bounds__(256)
void conv_s2(const float* __restrict__ in, const float* __restrict__ w,
             const float* __restrict__ bias, float* __restrict__ out,
             int Cout, int H, int W) {
  const int Ho = H >> 1, Wo = W >> 1;
  const int cogs = Cout / NC;
  const int gx  = blockIdx.x;
  const int cog = gx % cogs;
  const int b   = gx / cogs;
  const int co0 = cog * NC;
  const int Wq  = Wo / CPT;
  const int items = Ho * Wq;
  const int item  = blockIdx.y * 256 + threadIdx.x;
  if (item >= items) return;
  const int y  = item / Wq;
  const int x0 = (item - y * Wq) * CPT;
  const int ix = 2 * x0;

  const int HW = H * W;
  const float* ib = in + (size_t)b * CIN * HW;

  const int iy0 = 2 * y, iy1 = 2 * y + 1, iy2 = 2 * y + 2;
  const bool okB = (iy2 < H);
  const int iy2c = okB ? iy2 : 0;
  const bool okR = (ix + 2 * CPT < W);
  const int ixr  = okR ? (ix + 2 * CPT) : 0;

  float acc[NC][CPT];
  #pragma unroll
  for (int u = 0; u < NC; ++u)
    #pragma unroll
    for (int q = 0; q < CPT; ++q) acc[u][q] = 0.f;

  #pragma unroll 2
  for (int ci = 0; ci < CIN; ++ci) {
    const float* p = ib + ci * HW;
    const float* wci = w + ((size_t)co0 * CIN + ci) * 9;
    #pragma unroll
    for (int dy = 0; dy < 3; ++dy) {
      const int  ry    = (dy == 0) ? iy0 : ((dy == 1) ? iy1 : iy2c);
      const bool okRow = (dy < 2) || okB;
      const float* r = p + ry * W;
      float v[2 * CPT + 1];
      if (CPT == 4) {
        float4 m0 = *(const float4*)(r + ix);
        float4 m1 = *(const float4*)(r + ix + 4);
        float  rf = r[ixr];
        v[0] = okRow ? m0.x : 0.f; v[1] = okRow ? m0.y : 0.f;
        v[2] = okRow ? m0.z : 0.f; v[3] = okRow ? m0.w : 0.f;
        v[4] = okRow ? m1.x : 0.f; v[5] = okRow ? m1.y : 0.f;
        v[6] = okRow ? m1.z : 0.f; v[7] = okRow ? m1.w : 0.f;
        v[8] = (okRow && okR) ? rf : 0.f;
      } else if (CPT == 2) {
        float4 m0 = *(const float4*)(r + ix);
        float  rf = r[ixr];
        v[0] = okRow ? m0.x : 0.f; v[1] = okRow ? m0.y : 0.f;
        v[2] = okRow ? m0.z : 0.f; v[3] = okRow ? m0.w : 0.f;
        v[4] = (okRow && okR) ? rf : 0.f;
      } else {
        float2 m0 = *(const float2*)(r + ix);
        float  rf = r[ixr];
        v[0] = okRow ? m0.x : 0.f; v[1] = okRow ? m0.y : 0.f;
        v[2] = (okRow && okR) ? rf : 0.f;
      }
      #pragma unroll
      for (int u = 0; u < NC; ++u) {
        const float* wp = wci + u * CIN * 9 + dy * 3;
        const float w0 = wp[0], w1 = wp[1], w2 = wp[2];
        #pragma unroll
        for (int q = 0; q < CPT; ++q)
          acc[u][q] += v[2*q] * w0 + v[2*q + 1] * w1 + v[2*q + 2] * w2;
      }
    }
  }

  #pragma unroll
  for (int u = 0; u < NC; ++u) {
    const float bv = bias[co0 + u];
    float* op = out + ((size_t)(b * Cout + co0 + u) * Ho + y) * Wo + x0;
    if (CPT == 4) {
      float4 r4;
      r4.x = act_fn<ACT>(acc[u][0] + bv);
      r4.y = act_fn<ACT>(acc[u][1] + bv);
      r4.z = act_fn<ACT>(acc[u][2] + bv);
      r4.w = act_fn<ACT>(acc[u][3] + bv);
      *(float4*)op = r4;
    } else if (CPT == 2) {
      float2 r2;
      r2.x = act_fn<ACT>(acc[u][0] + bv);
      r2.y = act_fn<ACT>(acc[u][1] + bv);
      *(float2*)op = r2;
    } else {
      #pragma unroll
      for (int q = 0; q < CPT; ++q) op[q] = act_fn<ACT>(acc[u][q] + bv);
    }
  }
}

// ---------------- stride-2 3x3 SAME transposed conv ----------------------------
// out[2i,2j]=xtl*w00+xtr*w02+xbl*w20+xbr*w22; out[2i,2j+1]=xtr*w01+xbr*w21
// out[2i+1,2j]=xbl*w10+xbr*w12;               out[2i+1,2j+1]=xbr*w11
template<int ACT, int NC, int CIN>
__global__ __launch_bounds__(256)
void tconv(const float* __restrict__ in, const float* __restrict__ w,
           const float* __restrict__ bias, float* __restrict__ out,
           int Cout, int Hin) {
  const int cogs = Cout / NC;
  const int gx  = blockIdx.x;
  const int cog = gx % cogs;
  const int b   = gx / cogs;
  const int co0 = cog * NC;
  const int items = Hin * Hin;
  const int item  = blockIdx.y * 256 + threadIdx.x;
  if (item >= items) return;
  const int i = item / Hin;
  const int j = item - i * Hin;

  const float* ib = in + (size_t)b * CIN * items;
  const bool okT = (i > 0), okL = (j > 0);
  const int im = okT ? i - 1 : 0;
  const int jm = okL ? j - 1 : 0;

  float a00[NC], a01[NC], a10[NC], a11[NC];
  #pragma unroll
  for (int u = 0; u < NC; ++u) { a00[u]=0.f; a01[u]=0.f; a10[u]=0.f; a11[u]=0.f; }

  #pragma unroll 2
  for (int ci = 0; ci < CIN; ++ci) {
    const float* p = ib + ci * items;
    float xtl = p[im*Hin + jm]; xtl = (okT && okL) ? xtl : 0.f;
    float xtr = p[im*Hin + j];  xtr = okT ? xtr : 0.f;
    float xbl = p[i*Hin + jm];  xbl = okL ? xbl : 0.f;
    float xbr = p[i*Hin + j];
    const float* wci = w + ((size_t)co0 * CIN + ci) * 9;
    #pragma unroll
    for (int u = 0; u < NC; ++u) {
      const float* wp = wci + u * CIN * 9;
      const float w00 = wp[0], w01 = wp[1], w02 = wp[2];
      const float w10 = wp[3], w11 = wp[4], w12 = wp[5];
      const float w20 = wp[6], w21 = wp[7], w22 = wp[8];
      a00[u] += xtl*w00 + xtr*w02 + xbl*w20 + xbr*w22;
      a01[u] += xtr*w01 + xbr*w21;
      a10[u] += xbl*w10 + xbr*w12;
      a11[u] += xbr*w11;
    }
  }

  const int Ho = Hin * 2;
  #pragma unroll
  for (int u = 0; u < NC; ++u) {
    const float bv = bias[co0 + u];
    float* op = out + (size_t)(b * Cout + co0 + u) * Ho * Ho + (2*i) * Ho + 2*j;
    float2 t0, t1;
    t0.x = act_fn<ACT>(a00[u] + bv); t0.y = act_fn<ACT>(a01[u] + bv);
    t1.x = act_fn<ACT>(a10[u] + bv); t1.y = act_fn<ACT>(a11[u] + bv);
    *(float2*)op = t0;
    *(float2*)(op + Ho) = t1;
  }
}

// ---------------- keypoint reductions: S = sum R, Sh = sum R*h, Sw = sum R*w ----
__global__ __launch_bounds__(64)
void kp_reduce(const float* __restrict__ R, float* __restrict__ S,
               float* __restrict__ Sh, float* __restrict__ Sw) {
  const int bk = blockIdx.x;       // b*K + k, 16x16 maps
  const int t = threadIdx.x;       // 64
  const float* p = R + (size_t)bk * 256;
  float s = 0.f, sh = 0.f, sw = 0.f;
  #pragma unroll
  for (int q = 0; q < 4; ++q) {
    int idx = t + q * 64;
    float v = p[idx];
    s  += v;
    sh += v * (float)(idx >> 4);
    sw += v * (float)(idx & 15);
  }
  #pragma unroll
  for (int off = 32; off > 0; off >>= 1) {
    s  += __shfl_down(s, off);
    sh += __shfl_down(sh, off);
    sw += __shfl_down(sw, off);
  }
  if (t == 0) { S[bk] = s; Sh[bk] = sh; Sw[bk] = sw; }
}

// ---------------- gaussian blob maps -------------------------------------------
__global__ __launch_bounds__(256)
void kp_maps(const float* __restrict__ S, const float* __restrict__ Sh,
             const float* __restrict__ Sw, float* __restrict__ maps, int K) {
  const int bk = blockIdx.x;
  const int b = bk / K;
  const int t = threadIdx.x;       // 256 = 16x16
  const float s   = S[bk];
  const float den = S[b * K + (K - 1)];
  const float mu  = s * (1.0f / 256.0f);
  const float c0  = Sh[bk] / den;
  const float c1  = Sw[bk] / den;
  const float u = (float)(t >> 4);
  const float v = (float)(t & 15);
  const float d2 = (u - c0) * (u - c0) + (v - c1) * (v - c1);
  maps[(size_t)bk * 256 + t] = mu * expf(-0.5f * d2);
}

extern "C" void kernel_launch(void* const* d_in, const int* in_sizes, int n_in,
                              void* d_out, int out_size, void* d_ws, size_t ws_size,
                              hipStream_t stream) {
  const int B = 32;  // 4 * 8
  const float* x = (const float*)d_in[0];
  const float* ew[7]; const float* eb[7];
  for (int j = 0; j < 7; ++j) { ew[j] = (const float*)d_in[1 + 2*j]; eb[j] = (const float*)d_in[2 + 2*j]; }
  const float* dw[6]; const float* db[6];
  for (int j = 0; j < 6; ++j) { dw[j] = (const float*)d_in[15 + 2*j]; db[j] = (const float*)d_in[16 + 2*j]; }

  float* ws   = (float*)d_ws;
  float* bufA = ws;                       // 32*32*128*128 = 16,777,216 floats
  float* bufB = bufA + 16777216;
  float* R    = bufB + 16777216;          // 32*128*256 = 1,048,576
  float* maps = R + 1048576;
  float* S    = maps + 1048576;           // 4096
  float* Sh   = S + 4096;
  float* Sw   = Sh + 4096;
  float* outp = (float*)d_out;            // 32*16*128*128

  dim3 blk(256);

  // ---- encoder ---- (R17 config; enc0 -> full-unroll variant)
  conv_s1r2f<ACT_ID,   8,4,3>  <<<dim3(B*4,   8), blk, 0, stream>>>(x,    ew[0], eb[0], bufA, 32,  128, 128); // 1024
  conv_s1r2<ACT_ID,    8,4,32> <<<dim3(B*4,   8), blk, 0, stream>>>(bufA, ew[1], eb[1], bufB, 32,  128, 128); // 1024
  conv_s2<ACT_LRELU,   8,4,32> <<<dim3(B*8,   4), blk, 0, stream>>>(bufB, ew[2], eb[2], bufA, 64,  128, 128); // 1024
  conv_s1r2<ACT_LRELU, 4,4,64> <<<dim3(B*16,  2), blk, 0, stream>>>(bufA, ew[3], eb[3], bufB, 64,  64,  64);  // 1024
  conv_s2<ACT_LRELU,   8,2,64> <<<dim3(B*16,  2), blk, 0, stream>>>(bufB, ew[4], eb[4], bufA, 128, 64,  64);  // 1024
  conv32_lds<ACT_LRELU,4,128>  <<<dim3(B*32),     blk, 0, stream>>>(bufA, ew[5], eb[5], bufB, 128);           // 1024
  conv_s2<ACT_SOFTPLUS,4,1,128><<<dim3(B*32,  1), blk, 0, stream>>>(bufB, ew[6], eb[6], R,    128, 32,  32);  // 1024

  // ---- keypoint bottleneck ----
  kp_reduce<<<dim3(B*128), dim3(64), 0, stream>>>(R, S, Sh, Sw);
  kp_maps  <<<dim3(B*128), blk, 0, stream>>>(S, Sh, Sw, maps, 128);

  // ---- decoder ---- (exact R17)
  tconv<ACT_RELU,   2,128> <<<dim3(B*32,  1), blk, 0, stream>>>(maps, dw[0], db[0], bufA, 64, 16);            // 1024
  conv32_lds<ACT_RELU,2,64><<<dim3(B*32),     blk, 0, stream>>>(bufA, dw[1], db[1], bufB, 64);                // 1024
  tconv<ACT_RELU,   4,64>  <<<dim3(B*8,   4), blk, 0, stream>>>(bufB, dw[2], db[2], bufA, 32, 32);            // 1024
  conv_s1r2<ACT_RELU,4,2,32><<<dim3(B*8,  4), blk, 0, stream>>>(bufA, dw[3], db[3], bufB, 32, 64, 64);        // 1024
  tconv<ACT_RELU,   8,32>  <<<dim3(B*2,  16), blk, 0, stream>>>(bufB, dw[4], db[4], bufA, 16, 64);            // 1024
  conv_s1r2<ACT_RELU,4,4,16><<<dim3(B*4,  8), blk, 0, stream>>>(bufA, dw[5], db[5], outp, 16, 128, 128);      // 1024
}

// Round 17
// 1152.310 us; speedup vs baseline: 1.1518x; 1.0049x over previous
//
#include <hip/hip_runtime.h>
#include <math.h>

// ULOSD keypoint autoencoder, fp32 direct convolutions.
// Round 20: R19 = 1158us best (enc0 full-unroll +30us). enc1's FETCH=137MB on
// a 64MB input = 2.1x over-fetch: grid.x=b*cogs+cog makes the 4 cogs of one
// batch CONSECUTIVE blocks -> round-robin dispatch puts them on 4 different
// XCDs -> each private L2 refetches the same input from HBM; inner-loop loads
// are ~900cy HBM misses instead of ~200cy L2 hits (the exposed latency behind
// VALUBusy 68% at 2 waves/SIMD). Fix = T1 XCD chunk swizzle (guide S5.5):
// conv_s1r2x uses 1D grid, bijective sw=(bid%8)*(nwg/8)+bid/8, decomposed
// cog-fastest so same-(b,ychunk) cogs are co-resident on ONE XCD sharing one
// L2 copy. Applied to enc1 and enc3 (both exactly 1024 blocks). Pure index
// remap, zero compute change. Everything else exactly R19.

enum { ACT_ID = 0, ACT_LRELU = 1, ACT_SOFTPLUS = 2, ACT_RELU = 3 };

template<int ACT>
__device__ __forceinline__ float act_fn(float x) {
  if (ACT == ACT_LRELU)    return x >= 0.f ? x : 0.2f * x;
  if (ACT == ACT_SOFTPLUS) return fmaxf(x, 0.f) + log1pf(expf(-fabsf(x)));
  if (ACT == ACT_RELU)     return fmaxf(x, 0.f);
  return x;
}

// ---------------- 32x32 stride-1 conv, LDS plane-staged, 2x2 out per thread ----
template<int ACT, int NC, int CIN>
__global__ __launch_bounds__(256)
void conv32_lds(const float* __restrict__ in, const float* __restrict__ w,
                const float* __restrict__ bias, float* __restrict__ out,
                int Cout) {
  __shared__ float pl[2][32 * 36];
  const int cogs = Cout / NC;
  const int gx  = blockIdx.x;           // b*cogs + cog
  const int cog = gx % cogs;
  const int b   = gx / cogs;
  const int co0 = cog * NC;
  const int t   = threadIdx.x;
  const int x0  = (t & 15) * 2;         // output cols x0, x0+1
  const int y0  = (t >> 4) * 2;         // output rows y0, y0+1

  const float* ib = in + (size_t)b * CIN * 1024;
  const int lx = (t >> 3) * 36 + (t & 7) * 4;   // this thread's LDS stage slot

  {
    float4 g0 = *(const float4*)(ib + t * 4);
    *(float4*)&pl[0][lx] = g0;
  }
  __syncthreads();

  const bool okT = (y0 > 0), okB = (y0 + 2 < 32);
  const bool okL = (x0 > 0), okR = (x0 + 2 < 32);

  float acc[NC][2][2];
  #pragma unroll
  for (int u = 0; u < NC; ++u)
    #pragma unroll
    for (int o = 0; o < 2; ++o) { acc[u][o][0] = 0.f; acc[u][o][1] = 0.f; }

  int cur = 0;
  #pragma unroll 1
  for (int ci = 0; ci < CIN; ++ci) {
    const bool more = (ci + 1 < CIN);
    float4 g = {0.f, 0.f, 0.f, 0.f};
    if (more) g = *(const float4*)(ib + (size_t)(ci + 1) * 1024 + t * 4);

    const float* P = pl[cur];
    const float* wci = w + ((size_t)co0 * CIN + ci) * 9;
    #pragma unroll
    for (int r = 0; r < 4; ++r) {
      const bool ok = (r == 0) ? okT : ((r == 3) ? okB : true);
      const int ry = ok ? (y0 - 1 + r) : 0;
      const int base = ry * 36 + x0;
      float v[4];
      v[0] = (ok && okL) ? P[base - 1] : 0.f;
      v[1] = ok ? P[base]     : 0.f;
      v[2] = ok ? P[base + 1] : 0.f;
      v[3] = (ok && okR) ? P[base + 2] : 0.f;
      #pragma unroll
      for (int u = 0; u < NC; ++u) {
        const float* wp = wci + (size_t)u * CIN * 9;
        if (r <= 2) {
          const float w0 = wp[r * 3], w1 = wp[r * 3 + 1], w2 = wp[r * 3 + 2];
          acc[u][0][0] += v[0] * w0 + v[1] * w1 + v[2] * w2;
          acc[u][0][1] += v[1] * w0 + v[2] * w1 + v[3] * w2;
        }
        if (r >= 1) {
          const float w0 = wp[(r-1) * 3], w1 = wp[(r-1) * 3 + 1], w2 = wp[(r-1) * 3 + 2];
          acc[u][1][0] += v[0] * w0 + v[1] * w1 + v[2] * w2;
          acc[u][1][1] += v[1] * w0 + v[2] * w1 + v[3] * w2;
        }
      }
    }
    if (more) *(float4*)&pl[cur ^ 1][lx] = g;
    __syncthreads();
    cur ^= 1;
  }

  #pragma unroll
  for (int u = 0; u < NC; ++u) {
    const float bv = bias[co0 + u];
    float* op = out + ((size_t)(b * Cout + co0 + u) * 32 + y0) * 32 + x0;
    float2 r0, r1;
    r0.x = act_fn<ACT>(acc[u][0][0] + bv); r0.y = act_fn<ACT>(acc[u][0][1] + bv);
    r1.x = act_fn<ACT>(acc[u][1][0] + bv); r1.y = act_fn<ACT>(acc[u][1][1] + bv);
    *(float2*)op = r0;
    *(float2*)(op + 32) = r1;
  }
}

// ---------------- shared body for the s1r2 family ------------------------------
template<int ACT, int NC, int CPT, int CIN, int UNR>
__device__ __forceinline__ void s1r2_body(
    const float* __restrict__ in, const float* __restrict__ w,
    const float* __restrict__ bias, float* __restrict__ out,
    int Cout, int H, int W, int b, int co0, int item) {
  const int Wq = W / CPT;
  const int yp = item / Wq;
  const int x0 = (item - yp * Wq) * CPT;
  const int y0 = 2 * yp;                // output rows y0, y0+1; input y0-1..y0+2

  const int HW = H * W;
  const float* ib = in + (size_t)b * CIN * HW;

  const bool okT = (y0 > 0), okB = (y0 + 2 < H);
  const bool okL = (x0 > 0), okR = (x0 + CPT < W);
  const int xl = okL ? (x0 - 1) : 0;
  const int xr = okR ? (x0 + CPT) : 0;

  float acc[NC][2][CPT];
  #pragma unroll
  for (int u = 0; u < NC; ++u)
    #pragma unroll
    for (int o = 0; o < 2; ++o)
      #pragma unroll
      for (int q = 0; q < CPT; ++q) acc[u][o][q] = 0.f;

  #pragma unroll UNR
  for (int ci = 0; ci < CIN; ++ci) {
    const float* p = ib + ci * HW;
    const float* wci = w + ((size_t)co0 * CIN + ci) * 9;
    #pragma unroll
    for (int r = 0; r < 4; ++r) {            // input rows y0-1+r
      const bool ok = (r == 0) ? okT : ((r == 3) ? okB : true);
      const int iy = ok ? (y0 - 1 + r) : 0;
      const float* row = p + iy * W;
      float v[CPT + 2];
      if (CPT == 4) {
        float  lf = row[xl];
        float4 m  = *(const float4*)(row + x0);
        float  rf = row[xr];
        v[0] = (ok && okL) ? lf : 0.f;
        v[1] = ok ? m.x : 0.f;
        v[2] = ok ? m.y : 0.f;
        v[3] = ok ? m.z : 0.f;
        v[4] = ok ? m.w : 0.f;
        v[5] = (ok && okR) ? rf : 0.f;
      } else if (CPT == 2) {
        float  lf = row[xl];
        float2 m  = *(const float2*)(row + x0);   // x0 even -> aligned
        float  rf = row[xr];
        v[0] = (ok && okL) ? lf : 0.f;
        v[1] = ok ? m.x : 0.f;
        v[2] = ok ? m.y : 0.f;
        v[3] = (ok && okR) ? rf : 0.f;
      } else {
        v[0] = (ok && okL) ? row[xl] : 0.f;
        #pragma unroll
        for (int q = 0; q < CPT; ++q) v[1 + q] = ok ? row[x0 + q] : 0.f;
        v[CPT + 1] = (ok && okR) ? row[xr] : 0.f;
      }
      // input row r -> out-row0 with wrow r (r<=2), out-row1 with wrow r-1 (r>=1)
      #pragma unroll
      for (int u = 0; u < NC; ++u) {
        const float* wp = wci + (size_t)u * CIN * 9;   // wave-uniform s_loads
        if (r <= 2) {
          const float w0 = wp[r * 3], w1 = wp[r * 3 + 1], w2 = wp[r * 3 + 2];
          #pragma unroll
          for (int q = 0; q < CPT; ++q)
            acc[u][0][q] += v[q] * w0 + v[q + 1] * w1 + v[q + 2] * w2;
        }
        if (r >= 1) {
          const float w0 = wp[(r-1) * 3], w1 = wp[(r-1) * 3 + 1], w2 = wp[(r-1) * 3 + 2];
          #pragma unroll
          for (int q = 0; q < CPT; ++q)
            acc[u][1][q] += v[q] * w0 + v[q + 1] * w1 + v[q + 2] * w2;
        }
      }
    }
  }

  #pragma unroll
  for (int u = 0; u < NC; ++u) {
    const float bv = bias[co0 + u];
    float* op = out + ((size_t)(b * Cout + co0 + u) * H + y0) * W + x0;
    #pragma unroll
    for (int o = 0; o < 2; ++o) {
      float* opo = op + o * W;
      if (CPT == 4) {
        float4 r4;
        r4.x = act_fn<ACT>(acc[u][o][0] + bv);
        r4.y = act_fn<ACT>(acc[u][o][1] + bv);
        r4.z = act_fn<ACT>(acc[u][o][2] + bv);
        r4.w = act_fn<ACT>(acc[u][o][3] + bv);
        *(float4*)opo = r4;
      } else if (CPT == 2) {
        float2 r2;
        r2.x = act_fn<ACT>(acc[u][o][0] + bv);
        r2.y = act_fn<ACT>(acc[u][o][1] + bv);
        *(float2*)opo = r2;
      } else {
        #pragma unroll
        for (int q = 0; q < CPT; ++q) opo[q] = act_fn<ACT>(acc[u][o][q] + bv);
      }
    }
  }
}

// ---------------- stride-1 3x3 SAME conv, 2 output rows x CPT cols -------------
template<int ACT, int NC, int CPT, int CIN>
__global__ __launch_bounds__(256)
void conv_s1r2(const float* __restrict__ in, const float* __restrict__ w,
               const float* __restrict__ bias, float* __restrict__ out,
               int Cout, int H, int W) {
  const int cogs = Cout / NC;
  const int gx  = blockIdx.x;           // b*cogs + cog
  const int cog = gx % cogs;
  const int b   = gx / cogs;
  const int co0 = cog * NC;
  const int Wq  = W / CPT;
  const int items = (H >> 1) * Wq;
  const int item  = blockIdx.y * 256 + threadIdx.x;
  if (item >= items) return;
  s1r2_body<ACT, NC, CPT, CIN, 1>(in, w, bias, out, Cout, H, W, b, co0, item);
}

// ---------------- s1r2 with XCD chunk swizzle (T1), 1D grid --------------------
// nwg = B*cogs*YB must be divisible by 8. sw=(bid%8)*(nwg/8)+bid/8 groups the
// cogs of one (b, ychunk) onto one XCD so they share a single L2 input copy.
template<int ACT, int NC, int CPT, int CIN, int YB>
__global__ __launch_bounds__(256)
void conv_s1r2x(const float* __restrict__ in, const float* __restrict__ w,
                const float* __restrict__ bias, float* __restrict__ out,
                int Cout, int H, int W) {
  const int cogs = Cout / NC;
  const int nwg  = gridDim.x;
  const int q8   = nwg >> 3;
  const int bid  = blockIdx.x;
  const int sw   = (bid & 7) * q8 + (bid >> 3);   // bijective (nwg % 8 == 0)
  const int cog    = sw % cogs;                   // cog fastest -> co-resident
  const int rest   = sw / cogs;
  const int ychunk = rest % YB;
  const int b      = rest / YB;
  const int co0 = cog * NC;
  const int Wq  = W / CPT;
  const int items = (H >> 1) * Wq;
  const int item  = ychunk * 256 + threadIdx.x;
  if (item >= items) return;
  s1r2_body<ACT, NC, CPT, CIN, 1>(in, w, bias, out, Cout, H, W, b, co0, item);
}

// ---------------- same kernel, FULL ci unroll (small-CIN layers: enc0) ---------
template<int ACT, int NC, int CPT, int CIN>
__global__ __launch_bounds__(256)
void conv_s1r2f(const float* __restrict__ in, const float* __restrict__ w,
                const float* __restrict__ bias, float* __restrict__ out,
                int Cout, int H, int W) {
  const int cogs = Cout / NC;
  const int gx  = blockIdx.x;
  const int cog = gx % cogs;
  const int b   = gx / cogs;
  const int co0 = cog * NC;
  const int Wq  = W / CPT;
  const int items = (H >> 1) * Wq;
  const int item  = blockIdx.y * 256 + threadIdx.x;
  if (item >= items) return;
  s1r2_body<ACT, NC, CPT, CIN, CIN>(in, w, bias, out, Cout, H, W, b, co0, item);
}

// ---------------- stride-2 3x3 SAME conv (pad_before=0, pad_after=1) -----------
template<int ACT, int NC, int CPT, int CIN>
__global__ __launch_bounds__(256)
void conv_s2(const float* __restrict__ in, const float* __restrict__ w,
             const float* __restrict__ bias, float* __restrict__ out,
             int Cout, int H, int W) {
  const int Ho = H >> 1, Wo = W >> 1;
  const int cogs = Cout / NC;
  const int gx  = blockIdx.x;
  const int cog = gx % cogs;
  const int b   = gx / cogs;
  const int co0 = cog * NC;
  const int Wq  = Wo / CPT;
  const int items = Ho * Wq;
  const int item  = blockIdx.y * 256 + threadIdx.x;
  if (item >= items) return;
  const int y  = item / Wq;
  const int x0 = (item - y * Wq) * CPT;
  const int ix = 2 * x0;

  const int HW = H * W;
  const float* ib = in + (size_t)b * CIN * HW;

  const int iy0 = 2 * y, iy1 = 2 * y + 1, iy2 = 2 * y + 2;
  const bool okB = (iy2 < H);
  const int iy2c = okB ? iy2 : 0;
  const bool okR = (ix + 2 * CPT < W);
  const int ixr  = okR ? (ix + 2 * CPT) : 0;

  float acc[NC][CPT];
  #pragma unroll
  for (int u = 0; u < NC; ++u)
    #pragma unroll
    for (int q = 0; q < CPT; ++q) acc[u][q] = 0.f;

  #pragma unroll 2
  for (int ci = 0; ci < CIN; ++ci) {
    const float* p = ib + ci * HW;
    const float* wci = w + ((size_t)co0 * CIN + ci) * 9;
    #pragma unroll
    for (int dy = 0; dy < 3; ++dy) {
      const int  ry    = (dy == 0) ? iy0 : ((dy == 1) ? iy1 : iy2c);
      const bool okRow = (dy < 2) || okB;
      const float* r = p + ry * W;
      float v[2 * CPT + 1];
      if (CPT == 4) {
        float4 m0 = *(const float4*)(r + ix);
        float4 m1 = *(const float4*)(r + ix + 4);
        float  rf = r[ixr];
        v[0] = okRow ? m0.x : 0.f; v[1] = okRow ? m0.y : 0.f;
        v[2] = okRow ? m0.z : 0.f; v[3] = okRow ? m0.w : 0.f;
        v[4] = okRow ? m1.x : 0.f; v[5] = okRow ? m1.y : 0.f;
        v[6] = okRow ? m1.z : 0.f; v[7] = okRow ? m1.w : 0.f;
        v[8] = (okRow && okR) ? rf : 0.f;
      } else if (CPT == 2) {
        float4 m0 = *(const float4*)(r + ix);
        float  rf = r[ixr];
        v[0] = okRow ? m0.x : 0.f; v[1] = okRow ? m0.y : 0.f;
        v[2] = okRow ? m0.z : 0.f; v[3] = okRow ? m0.w : 0.f;
        v[4] = (okRow && okR) ? rf : 0.f;
      } else {
        float2 m0 = *(const float2*)(r + ix);
        float  rf = r[ixr];
        v[0] = okRow ? m0.x : 0.f; v[1] = okRow ? m0.y : 0.f;
        v[2] = (okRow && okR) ? rf : 0.f;
      }
      #pragma unroll
      for (int u = 0; u < NC; ++u) {
        const float* wp = wci + u * CIN * 9 + dy * 3;
        const float w0 = wp[0], w1 = wp[1], w2 = wp[2];
        #pragma unroll
        for (int q = 0; q < CPT; ++q)
          acc[u][q] += v[2*q] * w0 + v[2*q + 1] * w1 + v[2*q + 2] * w2;
      }
    }
  }

  #pragma unroll
  for (int u = 0; u < NC; ++u) {
    const float bv = bias[co0 + u];
    float* op = out + ((size_t)(b * Cout + co0 + u) * Ho + y) * Wo + x0;
    if (CPT == 4) {
      float4 r4;
      r4.x = act_fn<ACT>(acc[u][0] + bv);
      r4.y = act_fn<ACT>(acc[u][1] + bv);
      r4.z = act_fn<ACT>(acc[u][2] + bv);
      r4.w = act_fn<ACT>(acc[u][3] + bv);
      *(float4*)op = r4;
    } else if (CPT == 2) {
      float2 r2;
      r2.x = act_fn<ACT>(acc[u][0] + bv);
      r2.y = act_fn<ACT>(acc[u][1] + bv);
      *(float2*)op = r2;
    } else {
      #pragma unroll
      for (int q = 0; q < CPT; ++q) op[q] = act_fn<ACT>(acc[u][q] + bv);
    }
  }
}

// ---------------- stride-2 3x3 SAME transposed conv ----------------------------
// out[2i,2j]=xtl*w00+xtr*w02+xbl*w20+xbr*w22; out[2i,2j+1]=xtr*w01+xbr*w21
// out[2i+1,2j]=xbl*w10+xbr*w12;               out[2i+1,2j+1]=xbr*w11
template<int ACT, int NC, int CIN>
__global__ __launch_bounds__(256)
void tconv(const float* __restrict__ in, const float* __restrict__ w,
           const float* __restrict__ bias, float* __restrict__ out,
           int Cout, int Hin) {
  const int cogs = Cout / NC;
  const int gx  = blockIdx.x;
  const int cog = gx % cogs;
  const int b   = gx / cogs;
  const int co0 = cog * NC;
  const int items = Hin * Hin;
  const int item  = blockIdx.y * 256 + threadIdx.x;
  if (item >= items) return;
  const int i = item / Hin;
  const int j = item - i * Hin;

  const float* ib = in + (size_t)b * CIN * items;
  const bool okT = (i > 0), okL = (j > 0);
  const int im = okT ? i - 1 : 0;
  const int jm = okL ? j - 1 : 0;

  float a00[NC], a01[NC], a10[NC], a11[NC];
  #pragma unroll
  for (int u = 0; u < NC; ++u) { a00[u]=0.f; a01[u]=0.f; a10[u]=0.f; a11[u]=0.f; }

  #pragma unroll 2
  for (int ci = 0; ci < CIN; ++ci) {
    const float* p = ib + ci * items;
    float xtl = p[im*Hin + jm]; xtl = (okT && okL) ? xtl : 0.f;
    float xtr = p[im*Hin + j];  xtr = okT ? xtr : 0.f;
    float xbl = p[i*Hin + jm];  xbl = okL ? xbl : 0.f;
    float xbr = p[i*Hin + j];
    const float* wci = w + ((size_t)co0 * CIN + ci) * 9;
    #pragma unroll
    for (int u = 0; u < NC; ++u) {
      const float* wp = wci + u * CIN * 9;
      const float w00 = wp[0], w01 = wp[1], w02 = wp[2];
      const float w10 = wp[3], w11 = wp[4], w12 = wp[5];
      const float w20 = wp[6], w21 = wp[7], w22 = wp[8];
      a00[u] += xtl*w00 + xtr*w02 + xbl*w20 + xbr*w22;
      a01[u] += xtr*w01 + xbr*w21;
      a10[u] += xbl*w10 + xbr*w12;
      a11[u] += xbr*w11;
    }
  }

  const int Ho = Hin * 2;
  #pragma unroll
  for (int u = 0; u < NC; ++u) {
    const float bv = bias[co0 + u];
    float* op = out + (size_t)(b * Cout + co0 + u) * Ho * Ho + (2*i) * Ho + 2*j;
    float2 t0, t1;
    t0.x = act_fn<ACT>(a00[u] + bv); t0.y = act_fn<ACT>(a01[u] + bv);
    t1.x = act_fn<ACT>(a10[u] + bv); t1.y = act_fn<ACT>(a11[u] + bv);
    *(float2*)op = t0;
    *(float2*)(op + Ho) = t1;
  }
}

// ---------------- keypoint reductions: S = sum R, Sh = sum R*h, Sw = sum R*w ----
__global__ __launch_bounds__(64)
void kp_reduce(const float* __restrict__ R, float* __restrict__ S,
               float* __restrict__ Sh, float* __restrict__ Sw) {
  const int bk = blockIdx.x;       // b*K + k, 16x16 maps
  const int t = threadIdx.x;       // 64
  const float* p = R + (size_t)bk * 256;
  float s = 0.f, sh = 0.f, sw = 0.f;
  #pragma unroll
  for (int q = 0; q < 4; ++q) {
    int idx = t + q * 64;
    float v = p[idx];
    s  += v;
    sh += v * (float)(idx >> 4);
    sw += v * (float)(idx & 15);
  }
  #pragma unroll
  for (int off = 32; off > 0; off >>= 1) {
    s  += __shfl_down(s, off);
    sh += __shfl_down(sh, off);
    sw += __shfl_down(sw, off);
  }
  if (t == 0) { S[bk] = s; Sh[bk] = sh; Sw[bk] = sw; }
}

// ---------------- gaussian blob maps -------------------------------------------
__global__ __launch_bounds__(256)
void kp_maps(const float* __restrict__ S, const float* __restrict__ Sh,
             const float* __restrict__ Sw, float* __restrict__ maps, int K) {
  const int bk = blockIdx.x;
  const int b = bk / K;
  const int t = threadIdx.x;       // 256 = 16x16
  const float s   = S[bk];
  const float den = S[b * K + (K - 1)];
  const float mu  = s * (1.0f / 256.0f);
  const float c0  = Sh[bk] / den;
  const float c1  = Sw[bk] / den;
  const float u = (float)(t >> 4);
  const float v = (float)(t & 15);
  const float d2 = (u - c0) * (u - c0) + (v - c1) * (v - c1);
  maps[(size_t)bk * 256 + t] = mu * expf(-0.5f * d2);
}

extern "C" void kernel_launch(void* const* d_in, const int* in_sizes, int n_in,
                              void* d_out, int out_size, void* d_ws, size_t ws_size,
                              hipStream_t stream) {
  const int B = 32;  // 4 * 8
  const float* x = (const float*)d_in[0];
  const float* ew[7]; const float* eb[7];
  for (int j = 0; j < 7; ++j) { ew[j] = (const float*)d_in[1 + 2*j]; eb[j] = (const float*)d_in[2 + 2*j]; }
  const float* dw[6]; const float* db[6];
  for (int j = 0; j < 6; ++j) { dw[j] = (const float*)d_in[15 + 2*j]; db[j] = (const float*)d_in[16 + 2*j]; }

  float* ws   = (float*)d_ws;
  float* bufA = ws;                       // 32*32*128*128 = 16,777,216 floats
  float* bufB = bufA + 16777216;
  float* R    = bufB + 16777216;          // 32*128*256 = 1,048,576
  float* maps = R + 1048576;
  float* S    = maps + 1048576;           // 4096
  float* Sh   = S + 4096;
  float* Sw   = Sh + 4096;
  float* outp = (float*)d_out;            // 32*16*128*128

  dim3 blk(256);

  // ---- encoder ---- (R19 config; enc1/enc3 -> XCD-swizzled 1D grids)
  conv_s1r2f<ACT_ID,   8,4,3>    <<<dim3(B*4,   8), blk, 0, stream>>>(x,    ew[0], eb[0], bufA, 32,  128, 128); // 1024
  conv_s1r2x<ACT_ID,   8,4,32,8> <<<dim3(B*4*8),    blk, 0, stream>>>(bufA, ew[1], eb[1], bufB, 32,  128, 128); // 1024 (cogs4*YB8*B32)
  conv_s2<ACT_LRELU,   8,4,32>   <<<dim3(B*8,   4), blk, 0, stream>>>(bufB, ew[2], eb[2], bufA, 64,  128, 128); // 1024
  conv_s1r2x<ACT_LRELU,4,4,64,2> <<<dim3(B*16*2),   blk, 0, stream>>>(bufA, ew[3], eb[3], bufB, 64,  64,  64);  // 1024 (cogs16*YB2*B32)
  conv_s2<ACT_LRELU,   8,2,64>   <<<dim3(B*16,  2), blk, 0, stream>>>(bufB, ew[4], eb[4], bufA, 128, 64,  64);  // 1024
  conv32_lds<ACT_LRELU,4,128>    <<<dim3(B*32),     blk, 0, stream>>>(bufA, ew[5], eb[5], bufB, 128);           // 1024
  conv_s2<ACT_SOFTPLUS,4,1,128>  <<<dim3(B*32,  1), blk, 0, stream>>>(bufB, ew[6], eb[6], R,    128, 32,  32);  // 1024

  // ---- keypoint bottleneck ----
  kp_reduce<<<dim3(B*128), dim3(64), 0, stream>>>(R, S, Sh, Sw);
  kp_maps  <<<dim3(B*128), blk, 0, stream>>>(S, Sh, Sw, maps, 128);

  // ---- decoder ---- (exact R19)
  tconv<ACT_RELU,   2,128> <<<dim3(B*32,  1), blk, 0, stream>>>(maps, dw[0], db[0], bufA, 64, 16);            // 1024
  conv32_lds<ACT_RELU,2,64><<<dim3(B*32),     blk, 0, stream>>>(bufA, dw[1], db[1], bufB, 64);                // 1024
  tconv<ACT_RELU,   4,64>  <<<dim3(B*8,   4), blk, 0, stream>>>(bufB, dw[2], db[2], bufA, 32, 32);            // 1024
  conv_s1r2<ACT_RELU,4,2,32><<<dim3(B*8,  4), blk, 0, stream>>>(bufA, dw[3], db[3], bufB, 32, 64, 64);        // 1024
  tconv<ACT_RELU,   8,32>  <<<dim3(B*2,  16), blk, 0, stream>>>(bufB, dw[4], db[4], bufA, 16, 64);            // 1024
  conv_s1r2<ACT_RELU,4,4,16><<<dim3(B*4,  8), blk, 0, stream>>>(bufA, dw[5], db[5], outp, 16, 128, 128);      // 1024
}

// Round 18
// 1135.722 us; speedup vs baseline: 1.1686x; 1.0146x over previous
//
#include <hip/hip_runtime.h>
#include <math.h>

// ULOSD keypoint autoencoder, fp32 direct convolutions.
// Round 21: R20 = 1152us best. T1 swizzle on enc1 confirmed the XCD-L2 story
// emphatically: FETCH 137->17.6MB (7.8x), occ 25->40%, dur 200->185.6.
// New top: conv32_lds (enc5) at 185.5us with the same disease -- FETCH 66MB
// on a 16.8MB input (4x over-fetch; 32 consecutive cogs round-robined over
// 8 XCDs each re-pull the same 512KB planes). dec1 identical pattern.
// This round: conv32_ldsx = conv32_lds + the proven bijective chunk swizzle
// (nwg=1024 for both users, %8==0), cog-fastest decode -> each XCD chunk of
// 128 blocks = 4 full batches x 32 cogs sharing one L2 input copy.
// Zero compute/register change. Everything else exactly R20.

enum { ACT_ID = 0, ACT_LRELU = 1, ACT_SOFTPLUS = 2, ACT_RELU = 3 };

template<int ACT>
__device__ __forceinline__ float act_fn(float x) {
  if (ACT == ACT_LRELU)    return x >= 0.f ? x : 0.2f * x;
  if (ACT == ACT_SOFTPLUS) return fmaxf(x, 0.f) + log1pf(expf(-fabsf(x)));
  if (ACT == ACT_RELU)     return fmaxf(x, 0.f);
  return x;
}

// ---------------- 32x32 conv body: LDS plane-staged, 2x2 out per thread --------
template<int ACT, int NC, int CIN>
__device__ __forceinline__ void conv32_body(
    const float* __restrict__ in, const float* __restrict__ w,
    const float* __restrict__ bias, float* __restrict__ out,
    int Cout, int b, int co0, float (*pl)[32 * 36]) {
  const int t   = threadIdx.x;
  const int x0  = (t & 15) * 2;         // output cols x0, x0+1
  const int y0  = (t >> 4) * 2;         // output rows y0, y0+1

  const float* ib = in + (size_t)b * CIN * 1024;
  const int lx = (t >> 3) * 36 + (t & 7) * 4;   // this thread's LDS stage slot

  {
    float4 g0 = *(const float4*)(ib + t * 4);
    *(float4*)&pl[0][lx] = g0;
  }
  __syncthreads();

  const bool okT = (y0 > 0), okB = (y0 + 2 < 32);
  const bool okL = (x0 > 0), okR = (x0 + 2 < 32);

  float acc[NC][2][2];
  #pragma unroll
  for (int u = 0; u < NC; ++u)
    #pragma unroll
    for (int o = 0; o < 2; ++o) { acc[u][o][0] = 0.f; acc[u][o][1] = 0.f; }

  int cur = 0;
  #pragma unroll 1
  for (int ci = 0; ci < CIN; ++ci) {
    const bool more = (ci + 1 < CIN);
    float4 g = {0.f, 0.f, 0.f, 0.f};
    if (more) g = *(const float4*)(ib + (size_t)(ci + 1) * 1024 + t * 4);

    const float* P = pl[cur];
    const float* wci = w + ((size_t)co0 * CIN + ci) * 9;
    #pragma unroll
    for (int r = 0; r < 4; ++r) {
      const bool ok = (r == 0) ? okT : ((r == 3) ? okB : true);
      const int ry = ok ? (y0 - 1 + r) : 0;
      const int base = ry * 36 + x0;
      float v[4];
      v[0] = (ok && okL) ? P[base - 1] : 0.f;
      v[1] = ok ? P[base]     : 0.f;
      v[2] = ok ? P[base + 1] : 0.f;
      v[3] = (ok && okR) ? P[base + 2] : 0.f;
      #pragma unroll
      for (int u = 0; u < NC; ++u) {
        const float* wp = wci + (size_t)u * CIN * 9;
        if (r <= 2) {
          const float w0 = wp[r * 3], w1 = wp[r * 3 + 1], w2 = wp[r * 3 + 2];
          acc[u][0][0] += v[0] * w0 + v[1] * w1 + v[2] * w2;
          acc[u][0][1] += v[1] * w0 + v[2] * w1 + v[3] * w2;
        }
        if (r >= 1) {
          const float w0 = wp[(r-1) * 3], w1 = wp[(r-1) * 3 + 1], w2 = wp[(r-1) * 3 + 2];
          acc[u][1][0] += v[0] * w0 + v[1] * w1 + v[2] * w2;
          acc[u][1][1] += v[1] * w0 + v[2] * w1 + v[3] * w2;
        }
      }
    }
    if (more) *(float4*)&pl[cur ^ 1][lx] = g;
    __syncthreads();
    cur ^= 1;
  }

  #pragma unroll
  for (int u = 0; u < NC; ++u) {
    const float bv = bias[co0 + u];
    float* op = out + ((size_t)(b * Cout + co0 + u) * 32 + y0) * 32 + x0;
    float2 r0, r1;
    r0.x = act_fn<ACT>(acc[u][0][0] + bv); r0.y = act_fn<ACT>(acc[u][0][1] + bv);
    r1.x = act_fn<ACT>(acc[u][1][0] + bv); r1.y = act_fn<ACT>(acc[u][1][1] + bv);
    *(float2*)op = r0;
    *(float2*)(op + 32) = r1;
  }
}

// plain (kept for reference/other users): grid.x = b*cogs + cog
template<int ACT, int NC, int CIN>
__global__ __launch_bounds__(256)
void conv32_lds(const float* __restrict__ in, const float* __restrict__ w,
                const float* __restrict__ bias, float* __restrict__ out,
                int Cout) {
  __shared__ float pl[2][32 * 36];
  const int cogs = Cout / NC;
  const int gx  = blockIdx.x;
  const int cog = gx % cogs;
  const int b   = gx / cogs;
  conv32_body<ACT, NC, CIN>(in, w, bias, out, Cout, b, cog * NC, pl);
}

// XCD chunk-swizzled (T1): nwg % 8 == 0; cog fastest so same-b cogs co-reside
template<int ACT, int NC, int CIN>
__global__ __launch_bounds__(256)
void conv32_ldsx(const float* __restrict__ in, const float* __restrict__ w,
                 const float* __restrict__ bias, float* __restrict__ out,
                 int Cout) {
  __shared__ float pl[2][32 * 36];
  const int cogs = Cout / NC;
  const int nwg  = gridDim.x;
  const int q8   = nwg >> 3;
  const int bid  = blockIdx.x;
  const int sw   = (bid & 7) * q8 + (bid >> 3);   // bijective
  const int cog  = sw % cogs;
  const int b    = sw / cogs;
  conv32_body<ACT, NC, CIN>(in, w, bias, out, Cout, b, cog * NC, pl);
}

// ---------------- shared body for the s1r2 family ------------------------------
template<int ACT, int NC, int CPT, int CIN, int UNR>
__device__ __forceinline__ void s1r2_body(
    const float* __restrict__ in, const float* __restrict__ w,
    const float* __restrict__ bias, float* __restrict__ out,
    int Cout, int H, int W, int b, int co0, int item) {
  const int Wq = W / CPT;
  const int yp = item / Wq;
  const int x0 = (item - yp * Wq) * CPT;
  const int y0 = 2 * yp;                // output rows y0, y0+1; input y0-1..y0+2

  const int HW = H * W;
  const float* ib = in + (size_t)b * CIN * HW;

  const bool okT = (y0 > 0), okB = (y0 + 2 < H);
  const bool okL = (x0 > 0), okR = (x0 + CPT < W);
  const int xl = okL ? (x0 - 1) : 0;
  const int xr = okR ? (x0 + CPT) : 0;

  float acc[NC][2][CPT];
  #pragma unroll
  for (int u = 0; u < NC; ++u)
    #pragma unroll
    for (int o = 0; o < 2; ++o)
      #pragma unroll
      for (int q = 0; q < CPT; ++q) acc[u][o][q] = 0.f;

  #pragma unroll UNR
  for (int ci = 0; ci < CIN; ++ci) {
    const float* p = ib + ci * HW;
    const float* wci = w + ((size_t)co0 * CIN + ci) * 9;
    #pragma unroll
    for (int r = 0; r < 4; ++r) {            // input rows y0-1+r
      const bool ok = (r == 0) ? okT : ((r == 3) ? okB : true);
      const int iy = ok ? (y0 - 1 + r) : 0;
      const float* row = p + iy * W;
      float v[CPT + 2];
      if (CPT == 4) {
        float  lf = row[xl];
        float4 m  = *(const float4*)(row + x0);
        float  rf = row[xr];
        v[0] = (ok && okL) ? lf : 0.f;
        v[1] = ok ? m.x : 0.f;
        v[2] = ok ? m.y : 0.f;
        v[3] = ok ? m.z : 0.f;
        v[4] = ok ? m.w : 0.f;
        v[5] = (ok && okR) ? rf : 0.f;
      } else if (CPT == 2) {
        float  lf = row[xl];
        float2 m  = *(const float2*)(row + x0);   // x0 even -> aligned
        float  rf = row[xr];
        v[0] = (ok && okL) ? lf : 0.f;
        v[1] = ok ? m.x : 0.f;
        v[2] = ok ? m.y : 0.f;
        v[3] = (ok && okR) ? rf : 0.f;
      } else {
        v[0] = (ok && okL) ? row[xl] : 0.f;
        #pragma unroll
        for (int q = 0; q < CPT; ++q) v[1 + q] = ok ? row[x0 + q] : 0.f;
        v[CPT + 1] = (ok && okR) ? row[xr] : 0.f;
      }
      // input row r -> out-row0 with wrow r (r<=2), out-row1 with wrow r-1 (r>=1)
      #pragma unroll
      for (int u = 0; u < NC; ++u) {
        const float* wp = wci + (size_t)u * CIN * 9;   // wave-uniform s_loads
        if (r <= 2) {
          const float w0 = wp[r * 3], w1 = wp[r * 3 + 1], w2 = wp[r * 3 + 2];
          #pragma unroll
          for (int q = 0; q < CPT; ++q)
            acc[u][0][q] += v[q] * w0 + v[q + 1] * w1 + v[q + 2] * w2;
        }
        if (r >= 1) {
          const float w0 = wp[(r-1) * 3], w1 = wp[(r-1) * 3 + 1], w2 = wp[(r-1) * 3 + 2];
          #pragma unroll
          for (int q = 0; q < CPT; ++q)
            acc[u][1][q] += v[q] * w0 + v[q + 1] * w1 + v[q + 2] * w2;
        }
      }
    }
  }

  #pragma unroll
  for (int u = 0; u < NC; ++u) {
    const float bv = bias[co0 + u];
    float* op = out + ((size_t)(b * Cout + co0 + u) * H + y0) * W + x0;
    #pragma unroll
    for (int o = 0; o < 2; ++o) {
      float* opo = op + o * W;
      if (CPT == 4) {
        float4 r4;
        r4.x = act_fn<ACT>(acc[u][o][0] + bv);
        r4.y = act_fn<ACT>(acc[u][o][1] + bv);
        r4.z = act_fn<ACT>(acc[u][o][2] + bv);
        r4.w = act_fn<ACT>(acc[u][o][3] + bv);
        *(float4*)opo = r4;
      } else if (CPT == 2) {
        float2 r2;
        r2.x = act_fn<ACT>(acc[u][o][0] + bv);
        r2.y = act_fn<ACT>(acc[u][o][1] + bv);
        *(float2*)opo = r2;
      } else {
        #pragma unroll
        for (int q = 0; q < CPT; ++q) opo[q] = act_fn<ACT>(acc[u][o][q] + bv);
      }
    }
  }
}

// ---------------- stride-1 3x3 SAME conv, 2 output rows x CPT cols -------------
template<int ACT, int NC, int CPT, int CIN>
__global__ __launch_bounds__(256)
void conv_s1r2(const float* __restrict__ in, const float* __restrict__ w,
               const float* __restrict__ bias, float* __restrict__ out,
               int Cout, int H, int W) {
  const int cogs = Cout / NC;
  const int gx  = blockIdx.x;           // b*cogs + cog
  const int cog = gx % cogs;
  const int b   = gx / cogs;
  const int co0 = cog * NC;
  const int Wq  = W / CPT;
  const int items = (H >> 1) * Wq;
  const int item  = blockIdx.y * 256 + threadIdx.x;
  if (item >= items) return;
  s1r2_body<ACT, NC, CPT, CIN, 1>(in, w, bias, out, Cout, H, W, b, co0, item);
}

// ---------------- s1r2 with XCD chunk swizzle (T1), 1D grid --------------------
template<int ACT, int NC, int CPT, int CIN, int YB>
__global__ __launch_bounds__(256)
void conv_s1r2x(const float* __restrict__ in, const float* __restrict__ w,
                const float* __restrict__ bias, float* __restrict__ out,
                int Cout, int H, int W) {
  const int cogs = Cout / NC;
  const int nwg  = gridDim.x;
  const int q8   = nwg >> 3;
  const int bid  = blockIdx.x;
  const int sw   = (bid & 7) * q8 + (bid >> 3);   // bijective (nwg % 8 == 0)
  const int cog    = sw % cogs;                   // cog fastest -> co-resident
  const int rest   = sw / cogs;
  const int ychunk = rest % YB;
  const int b      = rest / YB;
  const int co0 = cog * NC;
  const int Wq  = W / CPT;
  const int items = (H >> 1) * Wq;
  const int item  = ychunk * 256 + threadIdx.x;
  if (item >= items) return;
  s1r2_body<ACT, NC, CPT, CIN, 1>(in, w, bias, out, Cout, H, W, b, co0, item);
}

// ---------------- same kernel, FULL ci unroll (small-CIN layers: enc0) ---------
template<int ACT, int NC, int CPT, int CIN>
__global__ __launch_bounds__(256)
void conv_s1r2f(const float* __restrict__ in, const float* __restrict__ w,
                const float* __restrict__ bias, float* __restrict__ out,
                int Cout, int H, int W) {
  const int cogs = Cout / NC;
  const int gx  = blockIdx.x;
  const int cog = gx % cogs;
  const int b   = gx / cogs;
  const int co0 = cog * NC;
  const int Wq  = W / CPT;
  const int items = (H >> 1) * Wq;
  const int item  = blockIdx.y * 256 + threadIdx.x;
  if (item >= items) return;
  s1r2_body<ACT, NC, CPT, CIN, CIN>(in, w, bias, out, Cout, H, W, b, co0, item);
}

// ---------------- stride-2 3x3 SAME conv (pad_before=0, pad_after=1) -----------
template<int ACT, int NC, int CPT, int CIN>
__global__ __launch_bounds__(256)
void conv_s2(const float* __restrict__ in, const float* __restrict__ w,
             const float* __restrict__ bias, float* __restrict__ out,
             int Cout, int H, int W) {
  const int Ho = H >> 1, Wo = W >> 1;
  const int cogs = Cout / NC;
  const int gx  = blockIdx.x;
  const int cog = gx % cogs;
  const int b   = gx / cogs;
  const int co0 = cog * NC;
  const int Wq  = Wo / CPT;
  const int items = Ho * Wq;
  const int item  = blockIdx.y * 256 + threadIdx.x;
  if (item >= items) return;
  const int y  = item / Wq;
  const int x0 = (item - y * Wq) * CPT;
  const int ix = 2 * x0;

  const int HW = H * W;
  const float* ib = in + (size_t)b * CIN * HW;

  const int iy0 = 2 * y, iy1 = 2 * y + 1, iy2 = 2 * y + 2;
  const bool okB = (iy2 < H);
  const int iy2c = okB ? iy2 : 0;
  const bool okR = (ix + 2 * CPT < W);
  const int ixr  = okR ? (ix + 2 * CPT) : 0;

  float acc[NC][CPT];
  #pragma unroll
  for (int u = 0; u < NC; ++u)
    #pragma unroll
    for (int q = 0; q < CPT; ++q) acc[u][q] = 0.f;

  #pragma unroll 2
  for (int ci = 0; ci < CIN; ++ci) {
    const float* p = ib + ci * HW;
    const float* wci = w + ((size_t)co0 * CIN + ci) * 9;
    #pragma unroll
    for (int dy = 0; dy < 3; ++dy) {
      const int  ry    = (dy == 0) ? iy0 : ((dy == 1) ? iy1 : iy2c);
      const bool okRow = (dy < 2) || okB;
      const float* r = p + ry * W;
      float v[2 * CPT + 1];
      if (CPT == 4) {
        float4 m0 = *(const float4*)(r + ix);
        float4 m1 = *(const float4*)(r + ix + 4);
        float  rf = r[ixr];
        v[0] = okRow ? m0.x : 0.f; v[1] = okRow ? m0.y : 0.f;
        v[2] = okRow ? m0.z : 0.f; v[3] = okRow ? m0.w : 0.f;
        v[4] = okRow ? m1.x : 0.f; v[5] = okRow ? m1.y : 0.f;
        v[6] = okRow ? m1.z : 0.f; v[7] = okRow ? m1.w : 0.f;
        v[8] = (okRow && okR) ? rf : 0.f;
      } else if (CPT == 2) {
        float4 m0 = *(const float4*)(r + ix);
        float  rf = r[ixr];
        v[0] = okRow ? m0.x : 0.f; v[1] = okRow ? m0.y : 0.f;
        v[2] = okRow ? m0.z : 0.f; v[3] = okRow ? m0.w : 0.f;
        v[4] = (okRow && okR) ? rf : 0.f;
      } else {
        float2 m0 = *(const float2*)(r + ix);
        float  rf = r[ixr];
        v[0] = okRow ? m0.x : 0.f; v[1] = okRow ? m0.y : 0.f;
        v[2] = (okRow && okR) ? rf : 0.f;
      }
      #pragma unroll
      for (int u = 0; u < NC; ++u) {
        const float* wp = wci + u * CIN * 9 + dy * 3;
        const float w0 = wp[0], w1 = wp[1], w2 = wp[2];
        #pragma unroll
        for (int q = 0; q < CPT; ++q)
          acc[u][q] += v[2*q] * w0 + v[2*q + 1] * w1 + v[2*q + 2] * w2;
      }
    }
  }

  #pragma unroll
  for (int u = 0; u < NC; ++u) {
    const float bv = bias[co0 + u];
    float* op = out + ((size_t)(b * Cout + co0 + u) * Ho + y) * Wo + x0;
    if (CPT == 4) {
      float4 r4;
      r4.x = act_fn<ACT>(acc[u][0] + bv);
      r4.y = act_fn<ACT>(acc[u][1] + bv);
      r4.z = act_fn<ACT>(acc[u][2] + bv);
      r4.w = act_fn<ACT>(acc[u][3] + bv);
      *(float4*)op = r4;
    } else if (CPT == 2) {
      float2 r2;
      r2.x = act_fn<ACT>(acc[u][0] + bv);
      r2.y = act_fn<ACT>(acc[u][1] + bv);
      *(float2*)op = r2;
    } else {
      #pragma unroll
      for (int q = 0; q < CPT; ++q) op[q] = act_fn<ACT>(acc[u][q] + bv);
    }
  }
}

// ---------------- stride-2 3x3 SAME transposed conv ----------------------------
// out[2i,2j]=xtl*w00+xtr*w02+xbl*w20+xbr*w22; out[2i,2j+1]=xtr*w01+xbr*w21
// out[2i+1,2j]=xbl*w10+xbr*w12;               out[2i+1,2j+1]=xbr*w11
template<int ACT, int NC, int CIN>
__global__ __launch_bounds__(256)
void tconv(const float* __restrict__ in, const float* __restrict__ w,
           const float* __restrict__ bias, float* __restrict__ out,
           int Cout, int Hin) {
  const int cogs = Cout / NC;
  const int gx  = blockIdx.x;
  const int cog = gx % cogs;
  const int b   = gx / cogs;
  const int co0 = cog * NC;
  const int items = Hin * Hin;
  const int item  = blockIdx.y * 256 + threadIdx.x;
  if (item >= items) return;
  const int i = item / Hin;
  const int j = item - i * Hin;

  const float* ib = in + (size_t)b * CIN * items;
  const bool okT = (i > 0), okL = (j > 0);
  const int im = okT ? i - 1 : 0;
  const int jm = okL ? j - 1 : 0;

  float a00[NC], a01[NC], a10[NC], a11[NC];
  #pragma unroll
  for (int u = 0; u < NC; ++u) { a00[u]=0.f; a01[u]=0.f; a10[u]=0.f; a11[u]=0.f; }

  #pragma unroll 2
  for (int ci = 0; ci < CIN; ++ci) {
    const float* p = ib + ci * items;
    float xtl = p[im*Hin + jm]; xtl = (okT && okL) ? xtl : 0.f;
    float xtr = p[im*Hin + j];  xtr = okT ? xtr : 0.f;
    float xbl = p[i*Hin + jm];  xbl = okL ? xbl : 0.f;
    float xbr = p[i*Hin + j];
    const float* wci = w + ((size_t)co0 * CIN + ci) * 9;
    #pragma unroll
    for (int u = 0; u < NC; ++u) {
      const float* wp = wci + u * CIN * 9;
      const float w00 = wp[0], w01 = wp[1], w02 = wp[2];
      const float w10 = wp[3], w11 = wp[4], w12 = wp[5];
      const float w20 = wp[6], w21 = wp[7], w22 = wp[8];
      a00[u] += xtl*w00 + xtr*w02 + xbl*w20 + xbr*w22;
      a01[u] += xtr*w01 + xbr*w21;
      a10[u] += xbl*w10 + xbr*w12;
      a11[u] += xbr*w11;
    }
  }

  const int Ho = Hin * 2;
  #pragma unroll
  for (int u = 0; u < NC; ++u) {
    const float bv = bias[co0 + u];
    float* op = out + (size_t)(b * Cout + co0 + u) * Ho * Ho + (2*i) * Ho + 2*j;
    float2 t0, t1;
    t0.x = act_fn<ACT>(a00[u] + bv); t0.y = act_fn<ACT>(a01[u] + bv);
    t1.x = act_fn<ACT>(a10[u] + bv); t1.y = act_fn<ACT>(a11[u] + bv);
    *(float2*)op = t0;
    *(float2*)(op + Ho) = t1;
  }
}

// ---------------- keypoint reductions: S = sum R, Sh = sum R*h, Sw = sum R*w ----
__global__ __launch_bounds__(64)
void kp_reduce(const float* __restrict__ R, float* __restrict__ S,
               float* __restrict__ Sh, float* __restrict__ Sw) {
  const int bk = blockIdx.x;       // b*K + k, 16x16 maps
  const int t = threadIdx.x;       // 64
  const float* p = R + (size_t)bk * 256;
  float s = 0.f, sh = 0.f, sw = 0.f;
  #pragma unroll
  for (int q = 0; q < 4; ++q) {
    int idx = t + q * 64;
    float v = p[idx];
    s  += v;
    sh += v * (float)(idx >> 4);
    sw += v * (float)(idx & 15);
  }
  #pragma unroll
  for (int off = 32; off > 0; off >>= 1) {
    s  += __shfl_down(s, off);
    sh += __shfl_down(sh, off);
    sw += __shfl_down(sw, off);
  }
  if (t == 0) { S[bk] = s; Sh[bk] = sh; Sw[bk] = sw; }
}

// ---------------- gaussian blob maps -------------------------------------------
__global__ __launch_bounds__(256)
void kp_maps(const float* __restrict__ S, const float* __restrict__ Sh,
             const float* __restrict__ Sw, float* __restrict__ maps, int K) {
  const int bk = blockIdx.x;
  const int b = bk / K;
  const int t = threadIdx.x;       // 256 = 16x16
  const float s   = S[bk];
  const float den = S[b * K + (K - 1)];
  const float mu  = s * (1.0f / 256.0f);
  const float c0  = Sh[bk] / den;
  const float c1  = Sw[bk] / den;
  const float u = (float)(t >> 4);
  const float v = (float)(t & 15);
  const float d2 = (u - c0) * (u - c0) + (v - c1) * (v - c1);
  maps[(size_t)bk * 256 + t] = mu * expf(-0.5f * d2);
}

extern "C" void kernel_launch(void* const* d_in, const int* in_sizes, int n_in,
                              void* d_out, int out_size, void* d_ws, size_t ws_size,
                              hipStream_t stream) {
  const int B = 32;  // 4 * 8
  const float* x = (const float*)d_in[0];
  const float* ew[7]; const float* eb[7];
  for (int j = 0; j < 7; ++j) { ew[j] = (const float*)d_in[1 + 2*j]; eb[j] = (const float*)d_in[2 + 2*j]; }
  const float* dw[6]; const float* db[6];
  for (int j = 0; j < 6; ++j) { dw[j] = (const float*)d_in[15 + 2*j]; db[j] = (const float*)d_in[16 + 2*j]; }

  float* ws   = (float*)d_ws;
  float* bufA = ws;                       // 32*32*128*128 = 16,777,216 floats
  float* bufB = bufA + 16777216;
  float* R    = bufB + 16777216;          // 32*128*256 = 1,048,576
  float* maps = R + 1048576;
  float* S    = maps + 1048576;           // 4096
  float* Sh   = S + 4096;
  float* Sw   = Sh + 4096;
  float* outp = (float*)d_out;            // 32*16*128*128

  dim3 blk(256);

  // ---- encoder ---- (R20 config; enc5 -> conv32_ldsx)
  conv_s1r2f<ACT_ID,   8,4,3>    <<<dim3(B*4,   8), blk, 0, stream>>>(x,    ew[0], eb[0], bufA, 32,  128, 128); // 1024
  conv_s1r2x<ACT_ID,   8,4,32,8> <<<dim3(B*4*8),    blk, 0, stream>>>(bufA, ew[1], eb[1], bufB, 32,  128, 128); // 1024
  conv_s2<ACT_LRELU,   8,4,32>   <<<dim3(B*8,   4), blk, 0, stream>>>(bufB, ew[2], eb[2], bufA, 64,  128, 128); // 1024
  conv_s1r2x<ACT_LRELU,4,4,64,2> <<<dim3(B*16*2),   blk, 0, stream>>>(bufA, ew[3], eb[3], bufB, 64,  64,  64);  // 1024
  conv_s2<ACT_LRELU,   8,2,64>   <<<dim3(B*16,  2), blk, 0, stream>>>(bufB, ew[4], eb[4], bufA, 128, 64,  64);  // 1024
  conv32_ldsx<ACT_LRELU,4,128>   <<<dim3(B*32),     blk, 0, stream>>>(bufA, ew[5], eb[5], bufB, 128);           // 1024
  conv_s2<ACT_SOFTPLUS,4,1,128>  <<<dim3(B*32,  1), blk, 0, stream>>>(bufB, ew[6], eb[6], R,    128, 32,  32);  // 1024

  // ---- keypoint bottleneck ----
  kp_reduce<<<dim3(B*128), dim3(64), 0, stream>>>(R, S, Sh, Sw);
  kp_maps  <<<dim3(B*128), blk, 0, stream>>>(S, Sh, Sw, maps, 128);

  // ---- decoder ---- (R20 config; dec1 -> conv32_ldsx)
  tconv<ACT_RELU,   2,128>  <<<dim3(B*32,  1), blk, 0, stream>>>(maps, dw[0], db[0], bufA, 64, 16);           // 1024
  conv32_ldsx<ACT_RELU,2,64><<<dim3(B*32),     blk, 0, stream>>>(bufA, dw[1], db[1], bufB, 64);               // 1024
  tconv<ACT_RELU,   4,64>   <<<dim3(B*8,   4), blk, 0, stream>>>(bufB, dw[2], db[2], bufA, 32, 32);           // 1024
  conv_s1r2<ACT_RELU,4,2,32><<<dim3(B*8,   4), blk, 0, stream>>>(bufA, dw[3], db[3], bufB, 32, 64, 64);       // 1024
  tconv<ACT_RELU,   8,32>   <<<dim3(B*2,  16), blk, 0, stream>>>(bufB, dw[4], db[4], bufA, 16, 64);           // 1024
  conv_s1r2<ACT_RELU,4,4,16><<<dim3(B*4,   8), blk, 0, stream>>>(bufA, dw[5], db[5], outp, 16, 128, 128);     // 1024
}